// Round 1
// baseline (7416.134 us; speedup 1.0000x reference)
//
#include <hip/hip_runtime.h>
#include <math.h>

#define S_LEN 2048
#define DMODEL 256
#define NHEAD 4
#define HDIM 64
#define NLAYER 4
#define FFDIM 2048
#define INDIM 512
#define BATCH 4
#define NTOK (BATCH * S_LEN) /* 8192 */
#define EPSV 1e-5f

// sin/cos positional encoding, matching the JAX reference:
// div_j = exp(-(2j) * ln(10000)/256); pe[s,2j]=sin(s*div), pe[s,2j+1]=cos(s*div)
__device__ __forceinline__ float pe_val(int s, int d) {
    const float c = 0.035977892f; // ln(10000)/256
    float dv = expf(-(float)(d & ~1) * c);
    float arg = (float)s * dv;
    return (d & 1) ? cosf(arg) : sinf(arg);
}

// ---------------------------------------------------------------------------
// GEMM: C[M,N] = A[M,K] @ W[N,K]^T + bias[N]
// MODE 0: bias only; 1: bias + positional encoding (input proj); 2: bias+relu
// 64x64 tile, BK=16, 256 threads, 4x4 microtile/thread.
// LDS stored k-major with pad 68 (16B-aligned rows, 2-way-max bank aliasing).
// ---------------------------------------------------------------------------
template <int MODE>
__global__ __launch_bounds__(256) void gemm_bt(const float* __restrict__ A,
                                               const float* __restrict__ W,
                                               const float* __restrict__ bias,
                                               float* __restrict__ C,
                                               int M, int N, int K)
{
    __shared__ float As[16][68];
    __shared__ float Ws[16][68];
    const int t = threadIdx.x;
    const int m0 = blockIdx.x * 64;
    const int n0 = blockIdx.y * 64;
    const int lrow = t >> 2;          // 0..63
    const int lcol = (t & 3) << 2;    // 0,4,8,12
    const int tx = t & 15;            // 0..15 (n)
    const int ty = t >> 4;            // 0..15 (m)

    const float* Ap = A + (size_t)(m0 + lrow) * K + lcol;
    const float* Wp = W + (size_t)(n0 + lrow) * K + lcol;

    float acc[4][4] = {{0.f, 0.f, 0.f, 0.f}, {0.f, 0.f, 0.f, 0.f},
                       {0.f, 0.f, 0.f, 0.f}, {0.f, 0.f, 0.f, 0.f}};

    for (int kb = 0; kb < K; kb += 16) {
        const float4 av = *(const float4*)(Ap + kb);
        const float4 wv = *(const float4*)(Wp + kb);
        __syncthreads();  // protect LDS from previous iteration's readers
        As[lcol + 0][lrow] = av.x; As[lcol + 1][lrow] = av.y;
        As[lcol + 2][lrow] = av.z; As[lcol + 3][lrow] = av.w;
        Ws[lcol + 0][lrow] = wv.x; Ws[lcol + 1][lrow] = wv.y;
        Ws[lcol + 2][lrow] = wv.z; Ws[lcol + 3][lrow] = wv.w;
        __syncthreads();
#pragma unroll
        for (int kk = 0; kk < 16; ++kk) {
            const float4 a = *(const float4*)&As[kk][ty << 2];
            const float4 w = *(const float4*)&Ws[kk][tx << 2];
            acc[0][0] += a.x * w.x; acc[0][1] += a.x * w.y;
            acc[0][2] += a.x * w.z; acc[0][3] += a.x * w.w;
            acc[1][0] += a.y * w.x; acc[1][1] += a.y * w.y;
            acc[1][2] += a.y * w.z; acc[1][3] += a.y * w.w;
            acc[2][0] += a.z * w.x; acc[2][1] += a.z * w.y;
            acc[2][2] += a.z * w.z; acc[2][3] += a.z * w.w;
            acc[3][0] += a.w * w.x; acc[3][1] += a.w * w.y;
            acc[3][2] += a.w * w.z; acc[3][3] += a.w * w.w;
        }
    }

    const int ncol = n0 + (tx << 2);
    const float4 bv = *(const float4*)&bias[ncol];
#pragma unroll
    for (int i = 0; i < 4; ++i) {
        const int row = m0 + (ty << 2) + i;
        float4 r;
        r.x = acc[i][0] + bv.x; r.y = acc[i][1] + bv.y;
        r.z = acc[i][2] + bv.z; r.w = acc[i][3] + bv.w;
        if (MODE == 1) {
            const int s = row & (S_LEN - 1);
            r.x += pe_val(s, ncol + 0); r.y += pe_val(s, ncol + 1);
            r.z += pe_val(s, ncol + 2); r.w += pe_val(s, ncol + 3);
        }
        if (MODE == 2) {
            r.x = fmaxf(r.x, 0.f); r.y = fmaxf(r.y, 0.f);
            r.z = fmaxf(r.z, 0.f); r.w = fmaxf(r.w, 0.f);
        }
        *(float4*)&C[(size_t)row * N + ncol] = r;
    }
}

// ---------------------------------------------------------------------------
// Flash-style attention. qkv: [NTOK, 768] (q|k|v each 256 = 4 heads x 64).
// One wave (64 threads) per (b, h, 64-query tile); each thread owns a query:
// q[64] and O[64] in registers, online softmax fully thread-local.
// K/V tiles (64x64 each) staged in LDS, read via broadcast.
// ---------------------------------------------------------------------------
__global__ __launch_bounds__(64, 1) void attn_kernel(const float* __restrict__ qkv,
                                                     float* __restrict__ ctx)
{
    __shared__ float kbuf[64][64];
    __shared__ float vbuf[64][64];
    const int tid = threadIdx.x;
    const int bh = blockIdx.x;   // 0..15
    const int qt = blockIdx.y;   // 0..31
    const int b = bh >> 2;
    const int hh = bh & 3;
    const int qi = qt * 64 + tid;

    const float* qp = qkv + (size_t)(b * S_LEN + qi) * 768 + hh * HDIM;
    float q[64];
#pragma unroll
    for (int i = 0; i < 16; ++i) {
        float4 v = *(const float4*)(qp + i * 4);
        q[i * 4 + 0] = v.x * 0.125f;  // scale = 1/sqrt(64) folded into q
        q[i * 4 + 1] = v.y * 0.125f;
        q[i * 4 + 2] = v.z * 0.125f;
        q[i * 4 + 3] = v.w * 0.125f;
    }
    float o[64];
#pragma unroll
    for (int i = 0; i < 64; ++i) o[i] = 0.f;
    float mmax = -1e30f, lsum = 0.f;

    const int srow_ld = tid >> 4;        // 0..3
    const int f_ld = (tid & 15) * 4;     // 0..60

    for (int kt = 0; kt < S_LEN / 64; ++kt) {
        __syncthreads();
#pragma unroll
        for (int rr = 0; rr < 16; ++rr) {
            const int row = rr * 4 + srow_ld;
            const float* kp =
                qkv + (size_t)(b * S_LEN + kt * 64 + row) * 768 + 256 + hh * HDIM + f_ld;
            *(float4*)&kbuf[row][f_ld] = *(const float4*)kp;
            *(float4*)&vbuf[row][f_ld] = *(const float4*)(kp + 256);
        }
        __syncthreads();

        for (int j = 0; j < 64; ++j) {
            float s0 = 0.f, s1 = 0.f, s2 = 0.f, s3 = 0.f;
#pragma unroll
            for (int d = 0; d < 64; d += 4) {
                const float4 kv = *(const float4*)&kbuf[j][d];
                s0 += q[d + 0] * kv.x; s1 += q[d + 1] * kv.y;
                s2 += q[d + 2] * kv.z; s3 += q[d + 3] * kv.w;
            }
            const float s = (s0 + s1) + (s2 + s3);
            if (s > mmax) {
                const float corr = __expf(mmax - s);
                lsum = lsum * corr + 1.f;
#pragma unroll
                for (int d = 0; d < 64; d += 4) {
                    const float4 vv = *(const float4*)&vbuf[j][d];
                    o[d + 0] = o[d + 0] * corr + vv.x;
                    o[d + 1] = o[d + 1] * corr + vv.y;
                    o[d + 2] = o[d + 2] * corr + vv.z;
                    o[d + 3] = o[d + 3] * corr + vv.w;
                }
                mmax = s;
            } else {
                const float p = __expf(s - mmax);
                lsum += p;
#pragma unroll
                for (int d = 0; d < 64; d += 4) {
                    const float4 vv = *(const float4*)&vbuf[j][d];
                    o[d + 0] += p * vv.x; o[d + 1] += p * vv.y;
                    o[d + 2] += p * vv.z; o[d + 3] += p * vv.w;
                }
            }
        }
    }

    const float inv = 1.f / lsum;
    float* op = ctx + (size_t)(b * S_LEN + qi) * DMODEL + hh * HDIM;
#pragma unroll
    for (int d = 0; d < 64; d += 4) {
        float4 r;
        r.x = o[d + 0] * inv; r.y = o[d + 1] * inv;
        r.z = o[d + 2] * inv; r.w = o[d + 3] * inv;
        *(float4*)(op + d) = r;
    }
}

// ---------------------------------------------------------------------------
// h[t] = LayerNorm(h[t] + r[t]) * w + b, one block per token, D=256 threads.
// var = E[x^2] - mu^2 (matches jnp.var denominator N).
// ---------------------------------------------------------------------------
__global__ __launch_bounds__(256) void add_ln(float* __restrict__ h,
                                              const float* __restrict__ r,
                                              const float* __restrict__ w,
                                              const float* __restrict__ b)
{
    const int t = blockIdx.x;
    const int d = threadIdx.x;
    const size_t idx = (size_t)t * DMODEL + d;
    const float x = h[idx] + r[idx];

    float s = x, s2 = x * x;
#pragma unroll
    for (int off = 32; off; off >>= 1) {
        s += __shfl_down(s, off);
        s2 += __shfl_down(s2, off);
    }
    __shared__ float ls[4], ls2[4];
    __shared__ float mu_s, rs_s;
    const int wid = d >> 6, lane = d & 63;
    if (lane == 0) { ls[wid] = s; ls2[wid] = s2; }
    __syncthreads();
    if (d == 0) {
        const float ts = ls[0] + ls[1] + ls[2] + ls[3];
        const float ts2 = ls2[0] + ls2[1] + ls2[2] + ls2[3];
        const float mu = ts * (1.f / DMODEL);
        const float var = ts2 * (1.f / DMODEL) - mu * mu;
        mu_s = mu;
        rs_s = rsqrtf(var + EPSV);
    }
    __syncthreads();
    h[idx] = (x - mu_s) * rs_s * w[d] + b[d];
}

// out[b, o] = h[b, S-1, :] . W_fc[o, :] + b_fc[o]; 2048 outputs total.
__global__ __launch_bounds__(256) void final_proj(const float* __restrict__ h,
                                                  const float* __restrict__ Wfc,
                                                  const float* __restrict__ bfc,
                                                  float* __restrict__ out)
{
    const int idx = blockIdx.x * 256 + threadIdx.x;  // 0..2047
    const int b = idx >> 9;
    const int o = idx & 511;
    const float* hp = h + (size_t)(b * S_LEN + S_LEN - 1) * DMODEL;
    const float* wp = Wfc + (size_t)o * DMODEL;
    float s = 0.f;
#pragma unroll 4
    for (int d = 0; d < DMODEL; ++d) s += hp[d] * wp[d];
    out[idx] = s + bfc[o];
}

extern "C" void kernel_launch(void* const* d_in, const int* in_sizes, int n_in,
                              void* d_out, int out_size, void* d_ws, size_t ws_size,
                              hipStream_t stream)
{
    const float* x     = (const float*)d_in[0];
    const float* W_in  = (const float*)d_in[1];
    const float* b_in  = (const float*)d_in[2];
    const float* qkv_w = (const float*)d_in[3];
    const float* qkv_b = (const float*)d_in[4];
    const float* out_w = (const float*)d_in[5];
    const float* out_b = (const float*)d_in[6];
    const float* ln1_w = (const float*)d_in[7];
    const float* ln1_b = (const float*)d_in[8];
    const float* ff1_w = (const float*)d_in[9];
    const float* ff1_b = (const float*)d_in[10];
    const float* ff2_w = (const float*)d_in[11];
    const float* ff2_b = (const float*)d_in[12];
    const float* ln2_w = (const float*)d_in[13];
    const float* ln2_b = (const float*)d_in[14];
    const float* W_fc  = (const float*)d_in[15];
    const float* b_fc  = (const float*)d_in[16];
    float* out = (float*)d_out;

    float* ws  = (float*)d_ws;
    float* h   = ws;                              // 8192*256  = 2,097,152
    float* qkv = h + (size_t)NTOK * DMODEL;       // 8192*768  = 6,291,456
    float* ctx = qkv + (size_t)NTOK * 768;        // 8192*256
    float* sa  = ctx + (size_t)NTOK * DMODEL;     // 8192*256
    float* ff  = sa + (size_t)NTOK * DMODEL;      // 8192*2048 = 16,777,216
    if (ws_size < (size_t)29360128 * 4) return;   // need ~112 MB

    // input projection + positional encoding
    gemm_bt<1><<<dim3(NTOK / 64, DMODEL / 64), 256, 0, stream>>>(
        x, W_in, b_in, h, NTOK, DMODEL, INDIM);

    for (int l = 0; l < NLAYER; ++l) {
        gemm_bt<0><<<dim3(NTOK / 64, 768 / 64), 256, 0, stream>>>(
            h, qkv_w + (size_t)l * 768 * DMODEL, qkv_b + l * 768, qkv,
            NTOK, 768, DMODEL);
        attn_kernel<<<dim3(BATCH * NHEAD, S_LEN / 64), 64, 0, stream>>>(qkv, ctx);
        gemm_bt<0><<<dim3(NTOK / 64, DMODEL / 64), 256, 0, stream>>>(
            ctx, out_w + (size_t)l * DMODEL * DMODEL, out_b + l * DMODEL, sa,
            NTOK, DMODEL, DMODEL);
        add_ln<<<NTOK, 256, 0, stream>>>(h, sa, ln1_w + l * DMODEL, ln1_b + l * DMODEL);
        gemm_bt<2><<<dim3(NTOK / 64, FFDIM / 64), 256, 0, stream>>>(
            h, ff1_w + (size_t)l * FFDIM * DMODEL, ff1_b + l * FFDIM, ff,
            NTOK, FFDIM, DMODEL);
        gemm_bt<0><<<dim3(NTOK / 64, DMODEL / 64), 256, 0, stream>>>(
            ff, ff2_w + (size_t)l * DMODEL * FFDIM, ff2_b + l * DMODEL, sa,
            NTOK, DMODEL, FFDIM);
        add_ln<<<NTOK, 256, 0, stream>>>(h, sa, ln2_w + l * DMODEL, ln2_b + l * DMODEL);
    }

    final_proj<<<8, 256, 0, stream>>>(h, W_fc, b_fc, out);
}

// Round 2
// 2034.159 us; speedup vs baseline: 3.6458x; 3.6458x over previous
//
#include <hip/hip_runtime.h>
#include <math.h>

#define S_LEN 2048
#define DMODEL 256
#define NHEAD 4
#define HDIM 64
#define NLAYER 4
#define FFDIM 2048
#define INDIM 512
#define BATCH 4
#define NTOK (BATCH * S_LEN) /* 8192 */
#define EPSV 1e-5f

// sin/cos positional encoding, matching the JAX reference
__device__ __forceinline__ float pe_val(int s, int d) {
    const float c = 0.035977892f; // ln(10000)/256
    float dv = expf(-(float)(d & ~1) * c);
    float arg = (float)s * dv;
    return (d & 1) ? cosf(arg) : sinf(arg);
}

// fp32 -> bf16 bits, round-to-nearest-even
__device__ __forceinline__ unsigned short f2bf(float f) {
    union { float f; unsigned u; } v; v.f = f;
    unsigned r = v.u + 0x7fffu + ((v.u >> 16) & 1u);
    return (unsigned short)(r >> 16);
}

// ---------------------------------------------------------------------------
// GEMM: C[M,N] = A[M,K] @ W[N,K]^T + bias[N]  (fp32, unchanged this round)
// MODE 0: bias only; 1: bias + positional encoding; 2: bias+relu
// ---------------------------------------------------------------------------
template <int MODE>
__global__ __launch_bounds__(256) void gemm_bt(const float* __restrict__ A,
                                               const float* __restrict__ W,
                                               const float* __restrict__ bias,
                                               float* __restrict__ C,
                                               int M, int N, int K)
{
    __shared__ float As[16][68];
    __shared__ float Ws[16][68];
    const int t = threadIdx.x;
    const int m0 = blockIdx.x * 64;
    const int n0 = blockIdx.y * 64;
    const int lrow = t >> 2;
    const int lcol = (t & 3) << 2;
    const int tx = t & 15;
    const int ty = t >> 4;

    const float* Ap = A + (size_t)(m0 + lrow) * K + lcol;
    const float* Wp = W + (size_t)(n0 + lrow) * K + lcol;

    float acc[4][4] = {{0.f, 0.f, 0.f, 0.f}, {0.f, 0.f, 0.f, 0.f},
                       {0.f, 0.f, 0.f, 0.f}, {0.f, 0.f, 0.f, 0.f}};

    for (int kb = 0; kb < K; kb += 16) {
        const float4 av = *(const float4*)(Ap + kb);
        const float4 wv = *(const float4*)(Wp + kb);
        __syncthreads();
        As[lcol + 0][lrow] = av.x; As[lcol + 1][lrow] = av.y;
        As[lcol + 2][lrow] = av.z; As[lcol + 3][lrow] = av.w;
        Ws[lcol + 0][lrow] = wv.x; Ws[lcol + 1][lrow] = wv.y;
        Ws[lcol + 2][lrow] = wv.z; Ws[lcol + 3][lrow] = wv.w;
        __syncthreads();
#pragma unroll
        for (int kk = 0; kk < 16; ++kk) {
            const float4 a = *(const float4*)&As[kk][ty << 2];
            const float4 w = *(const float4*)&Ws[kk][tx << 2];
            acc[0][0] += a.x * w.x; acc[0][1] += a.x * w.y;
            acc[0][2] += a.x * w.z; acc[0][3] += a.x * w.w;
            acc[1][0] += a.y * w.x; acc[1][1] += a.y * w.y;
            acc[1][2] += a.y * w.z; acc[1][3] += a.y * w.w;
            acc[2][0] += a.z * w.x; acc[2][1] += a.z * w.y;
            acc[2][2] += a.z * w.z; acc[2][3] += a.z * w.w;
            acc[3][0] += a.w * w.x; acc[3][1] += a.w * w.y;
            acc[3][2] += a.w * w.z; acc[3][3] += a.w * w.w;
        }
    }

    const int ncol = n0 + (tx << 2);
    const float4 bv = *(const float4*)&bias[ncol];
#pragma unroll
    for (int i = 0; i < 4; ++i) {
        const int row = m0 + (ty << 2) + i;
        float4 r;
        r.x = acc[i][0] + bv.x; r.y = acc[i][1] + bv.y;
        r.z = acc[i][2] + bv.z; r.w = acc[i][3] + bv.w;
        if (MODE == 1) {
            const int s = row & (S_LEN - 1);
            r.x += pe_val(s, ncol + 0); r.y += pe_val(s, ncol + 1);
            r.z += pe_val(s, ncol + 2); r.w += pe_val(s, ncol + 3);
        }
        if (MODE == 2) {
            r.x = fmaxf(r.x, 0.f); r.y = fmaxf(r.y, 0.f);
            r.z = fmaxf(r.z, 0.f); r.w = fmaxf(r.w, 0.f);
        }
        *(float4*)&C[(size_t)row * N + ncol] = r;
    }
}

// ---------------------------------------------------------------------------
// Flash attention via bf16 MFMA (16x16x32).
// Block = 256 thr = 4 waves, 64 queries/block (16/wave). K-tiles of 64 keys.
// LDS: Ks[key][dim] (B-frag for QK^T), Vt[dim][key] (B-frag for PV),
//      Ps[wave][q][key] (P round-trip C-layout -> A-layout, m120 pattern).
// Rows padded to 72 bf16 (144 B = 9 superbanks) -> conflict-free b128 reads.
// A-frag: lane holds A[m=lane&15][k=quad*8+j]; B-frag: B[k=quad*8+j][n=lane&15];
// C/D: D[row=quad*4+reg][col=lane&15] (m89/m91-verified layouts).
// ---------------------------------------------------------------------------
#define PADW 72
typedef __attribute__((ext_vector_type(8))) short frag8;
typedef __attribute__((ext_vector_type(4))) float f32x4v;

__global__ __launch_bounds__(256) void attn_mfma(const float* __restrict__ qkv,
                                                 float* __restrict__ ctx)
{
    __shared__ __align__(16) unsigned short Ks[64][PADW];
    __shared__ __align__(16) unsigned short Vt[64][PADW];
    __shared__ __align__(16) unsigned short Ps[4][16][PADW];

    const int t = threadIdx.x;
    const int w = t >> 6;          // wave 0..3
    const int lane = t & 63;
    const int col = lane & 15;     // m (A) / n (B,C) index
    const int quad = lane >> 4;    // 0..3

    const int bh = blockIdx.x;     // 0..15
    const int b = bh >> 2;
    const int hh = bh & 3;
    const int qt = blockIdx.y;     // 0..31

    // ---- Q fragments, scale 1/8 folded in, kept in regs all kernel ----
    const int qrow = qt * 64 + w * 16 + col;
    const float* qp = qkv + (size_t)(b * S_LEN + qrow) * 768 + hh * HDIM;
    frag8 qf[2];
#pragma unroll
    for (int ks = 0; ks < 2; ++ks) {
        const float4 a = *(const float4*)(qp + ks * 32 + quad * 8);
        const float4 c = *(const float4*)(qp + ks * 32 + quad * 8 + 4);
        qf[ks][0] = (short)f2bf(a.x * 0.125f); qf[ks][1] = (short)f2bf(a.y * 0.125f);
        qf[ks][2] = (short)f2bf(a.z * 0.125f); qf[ks][3] = (short)f2bf(a.w * 0.125f);
        qf[ks][4] = (short)f2bf(c.x * 0.125f); qf[ks][5] = (short)f2bf(c.y * 0.125f);
        qf[ks][6] = (short)f2bf(c.z * 0.125f); qf[ks][7] = (short)f2bf(c.w * 0.125f);
    }

    f32x4v Oacc[4];
    float m_r[4], l_r[4];
#pragma unroll
    for (int nt = 0; nt < 4; ++nt) Oacc[nt] = (f32x4v){0.f, 0.f, 0.f, 0.f};
#pragma unroll
    for (int r = 0; r < 4; ++r) { m_r[r] = -1e30f; l_r[r] = 0.f; }

    // staging mapping: thread covers dims dcol..dcol+3 of keys kg*4..kg*4+3
    const int dcol = (t & 15) * 4;
    const int kg = t >> 4;

    for (int kt = 0; kt < S_LEN / 64; ++kt) {
        __syncthreads();  // previous tile's readers done
        float vreg[4][4];
#pragma unroll
        for (int r = 0; r < 4; ++r) {
            const int key = kg * 4 + r;
            const float* kp = qkv + (size_t)(b * S_LEN + kt * 64 + key) * 768
                              + 256 + hh * HDIM + dcol;
            const float4 kv = *(const float4*)kp;
            ushort4 kb;
            kb.x = f2bf(kv.x); kb.y = f2bf(kv.y);
            kb.z = f2bf(kv.z); kb.w = f2bf(kv.w);
            *(ushort4*)&Ks[key][dcol] = kb;
            const float4 vv = *(const float4*)(kp + 256);
            vreg[r][0] = vv.x; vreg[r][1] = vv.y; vreg[r][2] = vv.z; vreg[r][3] = vv.w;
        }
#pragma unroll
        for (int dd = 0; dd < 4; ++dd) {   // transpose V into Vt[dim][key]
            ushort4 vb;
            vb.x = f2bf(vreg[0][dd]); vb.y = f2bf(vreg[1][dd]);
            vb.z = f2bf(vreg[2][dd]); vb.w = f2bf(vreg[3][dd]);
            *(ushort4*)&Vt[dcol + dd][kg * 4] = vb;
        }
        __syncthreads();

        // ---- S = Q K^T (16q x 64keys per wave) ----
        f32x4v S[4];
#pragma unroll
        for (int nt = 0; nt < 4; ++nt) {
            const frag8 k0 = *(const frag8*)&Ks[nt * 16 + col][quad * 8];
            const frag8 k1 = *(const frag8*)&Ks[nt * 16 + col][32 + quad * 8];
            f32x4v s = (f32x4v){0.f, 0.f, 0.f, 0.f};
            s = __builtin_amdgcn_mfma_f32_16x16x32_bf16(qf[0], k0, s, 0, 0, 0);
            s = __builtin_amdgcn_mfma_f32_16x16x32_bf16(qf[1], k1, s, 0, 0, 0);
            S[nt] = s;
        }

        // ---- online softmax (row q = quad*4+reg, cols spread over 16 lanes) ----
        float mt[4];
#pragma unroll
        for (int r = 0; r < 4; ++r) {
            mt[r] = fmaxf(fmaxf(S[0][r], S[1][r]), fmaxf(S[2][r], S[3][r]));
#pragma unroll
            for (int msk = 1; msk < 16; msk <<= 1)
                mt[r] = fmaxf(mt[r], __shfl_xor(mt[r], msk));
        }
        float alpha[4], psum[4];
#pragma unroll
        for (int r = 0; r < 4; ++r) {
            const float mn = fmaxf(m_r[r], mt[r]);
            alpha[r] = __expf(m_r[r] - mn);
            m_r[r] = mn;
            psum[r] = 0.f;
        }
#pragma unroll
        for (int nt = 0; nt < 4; ++nt) {
#pragma unroll
            for (int r = 0; r < 4; ++r) {
                const float p = __expf(S[nt][r] - m_r[r]);
                S[nt][r] = p;
                psum[r] += p;
                Ps[w][quad * 4 + r][nt * 16 + col] = f2bf(p);
            }
        }
#pragma unroll
        for (int r = 0; r < 4; ++r) {
#pragma unroll
            for (int msk = 1; msk < 16; msk <<= 1)
                psum[r] += __shfl_xor(psum[r], msk);
            l_r[r] = l_r[r] * alpha[r] + psum[r];
        }
#pragma unroll
        for (int nt = 0; nt < 4; ++nt) {
#pragma unroll
            for (int r = 0; r < 4; ++r) Oacc[nt][r] *= alpha[r];
        }
        __syncthreads();  // P writes visible before frag reads (in-wave, but be safe)

        // ---- O += P V ----
        const frag8 p0 = *(const frag8*)&Ps[w][col][quad * 8];
        const frag8 p1 = *(const frag8*)&Ps[w][col][32 + quad * 8];
#pragma unroll
        for (int nt = 0; nt < 4; ++nt) {
            const frag8 v0 = *(const frag8*)&Vt[nt * 16 + col][quad * 8];
            const frag8 v1 = *(const frag8*)&Vt[nt * 16 + col][32 + quad * 8];
            Oacc[nt] = __builtin_amdgcn_mfma_f32_16x16x32_bf16(p0, v0, Oacc[nt], 0, 0, 0);
            Oacc[nt] = __builtin_amdgcn_mfma_f32_16x16x32_bf16(p1, v1, Oacc[nt], 0, 0, 0);
        }
    }

    // ---- epilogue: O / l -> ctx ----
    float inv[4];
#pragma unroll
    for (int r = 0; r < 4; ++r) inv[r] = 1.f / l_r[r];
    float* op = ctx + (size_t)(b * S_LEN + qt * 64 + w * 16) * DMODEL + hh * HDIM;
#pragma unroll
    for (int nt = 0; nt < 4; ++nt) {
#pragma unroll
        for (int r = 0; r < 4; ++r) {
            const int q = quad * 4 + r;
            op[(size_t)q * DMODEL + nt * 16 + col] = Oacc[nt][r] * inv[r];
        }
    }
}

// ---------------------------------------------------------------------------
// h[t] = LayerNorm(h[t] + r[t]) * w + b
// ---------------------------------------------------------------------------
__global__ __launch_bounds__(256) void add_ln(float* __restrict__ h,
                                              const float* __restrict__ r,
                                              const float* __restrict__ w,
                                              const float* __restrict__ b)
{
    const int t = blockIdx.x;
    const int d = threadIdx.x;
    const size_t idx = (size_t)t * DMODEL + d;
    const float x = h[idx] + r[idx];

    float s = x, s2 = x * x;
#pragma unroll
    for (int off = 32; off; off >>= 1) {
        s += __shfl_down(s, off);
        s2 += __shfl_down(s2, off);
    }
    __shared__ float ls[4], ls2[4];
    __shared__ float mu_s, rs_s;
    const int wid = d >> 6, lane = d & 63;
    if (lane == 0) { ls[wid] = s; ls2[wid] = s2; }
    __syncthreads();
    if (d == 0) {
        const float ts = ls[0] + ls[1] + ls[2] + ls[3];
        const float ts2 = ls2[0] + ls2[1] + ls2[2] + ls2[3];
        const float mu = ts * (1.f / DMODEL);
        const float var = ts2 * (1.f / DMODEL) - mu * mu;
        mu_s = mu;
        rs_s = rsqrtf(var + EPSV);
    }
    __syncthreads();
    h[idx] = (x - mu_s) * rs_s * w[d] + b[d];
}

__global__ __launch_bounds__(256) void final_proj(const float* __restrict__ h,
                                                  const float* __restrict__ Wfc,
                                                  const float* __restrict__ bfc,
                                                  float* __restrict__ out)
{
    const int idx = blockIdx.x * 256 + threadIdx.x;
    const int b = idx >> 9;
    const int o = idx & 511;
    const float* hp = h + (size_t)(b * S_LEN + S_LEN - 1) * DMODEL;
    const float* wp = Wfc + (size_t)o * DMODEL;
    float s = 0.f;
#pragma unroll 4
    for (int d = 0; d < DMODEL; ++d) s += hp[d] * wp[d];
    out[idx] = s + bfc[o];
}

extern "C" void kernel_launch(void* const* d_in, const int* in_sizes, int n_in,
                              void* d_out, int out_size, void* d_ws, size_t ws_size,
                              hipStream_t stream)
{
    const float* x     = (const float*)d_in[0];
    const float* W_in  = (const float*)d_in[1];
    const float* b_in  = (const float*)d_in[2];
    const float* qkv_w = (const float*)d_in[3];
    const float* qkv_b = (const float*)d_in[4];
    const float* out_w = (const float*)d_in[5];
    const float* out_b = (const float*)d_in[6];
    const float* ln1_w = (const float*)d_in[7];
    const float* ln1_b = (const float*)d_in[8];
    const float* ff1_w = (const float*)d_in[9];
    const float* ff1_b = (const float*)d_in[10];
    const float* ff2_w = (const float*)d_in[11];
    const float* ff2_b = (const float*)d_in[12];
    const float* ln2_w = (const float*)d_in[13];
    const float* ln2_b = (const float*)d_in[14];
    const float* W_fc  = (const float*)d_in[15];
    const float* b_fc  = (const float*)d_in[16];
    float* out = (float*)d_out;

    float* ws  = (float*)d_ws;
    float* h   = ws;
    float* qkv = h + (size_t)NTOK * DMODEL;
    float* ctx = qkv + (size_t)NTOK * 768;
    float* sa  = ctx + (size_t)NTOK * DMODEL;
    float* ff  = sa + (size_t)NTOK * DMODEL;
    if (ws_size < (size_t)29360128 * 4) return;

    gemm_bt<1><<<dim3(NTOK / 64, DMODEL / 64), 256, 0, stream>>>(
        x, W_in, b_in, h, NTOK, DMODEL, INDIM);

    for (int l = 0; l < NLAYER; ++l) {
        gemm_bt<0><<<dim3(NTOK / 64, 768 / 64), 256, 0, stream>>>(
            h, qkv_w + (size_t)l * 768 * DMODEL, qkv_b + l * 768, qkv,
            NTOK, 768, DMODEL);
        attn_mfma<<<dim3(BATCH * NHEAD, S_LEN / 64), 256, 0, stream>>>(qkv, ctx);
        gemm_bt<0><<<dim3(NTOK / 64, DMODEL / 64), 256, 0, stream>>>(
            ctx, out_w + (size_t)l * DMODEL * DMODEL, out_b + l * DMODEL, sa,
            NTOK, DMODEL, DMODEL);
        add_ln<<<NTOK, 256, 0, stream>>>(h, sa, ln1_w + l * DMODEL, ln1_b + l * DMODEL);
        gemm_bt<2><<<dim3(NTOK / 64, FFDIM / 64), 256, 0, stream>>>(
            h, ff1_w + (size_t)l * FFDIM * DMODEL, ff1_b + l * FFDIM, ff,
            NTOK, FFDIM, DMODEL);
        gemm_bt<0><<<dim3(NTOK / 64, DMODEL / 64), 256, 0, stream>>>(
            ff, ff2_w + (size_t)l * DMODEL * FFDIM, ff2_b + l * DMODEL, sa,
            NTOK, DMODEL, FFDIM);
        add_ln<<<NTOK, 256, 0, stream>>>(h, sa, ln2_w + l * DMODEL, ln2_b + l * DMODEL);
    }

    final_proj<<<8, 256, 0, stream>>>(h, W_fc, b_fc, out);
}

// Round 3
// 890.404 us; speedup vs baseline: 8.3290x; 2.2845x over previous
//
#include <hip/hip_runtime.h>
#include <math.h>

#define S_LEN 2048
#define DMODEL 256
#define NHEAD 4
#define HDIM 64
#define NLAYER 4
#define FFDIM 2048
#define INDIM 512
#define BATCH 4
#define NTOK (BATCH * S_LEN) /* 8192 */
#define EPSV 1e-5f

typedef __attribute__((ext_vector_type(8))) short frag8;
typedef __attribute__((ext_vector_type(4))) float f32x4v;
typedef unsigned short u16;

// sin/cos positional encoding, matching the JAX reference
__device__ __forceinline__ float pe_val(int s, int d) {
    const float c = 0.035977892f; // ln(10000)/256
    float dv = expf(-(float)(d & ~1) * c);
    float arg = (float)s * dv;
    return (d & 1) ? cosf(arg) : sinf(arg);
}

// fp32 -> bf16 bits, round-to-nearest-even
__device__ __forceinline__ u16 f2bf(float f) {
    union { float f; unsigned u; } v; v.f = f;
    unsigned r = v.u + 0x7fffu + ((v.u >> 16) & 1u);
    return (u16)(r >> 16);
}

// async global->LDS, 16 B per lane; LDS dest = wave-uniform base + lane*16
__device__ __forceinline__ void load_lds16(const u16* g, u16* l) {
    __builtin_amdgcn_global_load_lds(
        (const __attribute__((address_space(1))) unsigned int*)g,
        (__attribute__((address_space(3))) unsigned int*)l, 16, 0, 0);
}

// ---------------------------------------------------------------------------
// Convert x + all layer weights fp32 -> bf16 (one launch, float4 granules).
// Segment bounds in float4 units (sizes/4), hardcoded for this model.
// ---------------------------------------------------------------------------
__global__ __launch_bounds__(256) void cvt_all(
    const float* __restrict__ x, const float* __restrict__ W_in,
    const float* __restrict__ qkv_w, const float* __restrict__ out_w,
    const float* __restrict__ ff1_w, const float* __restrict__ ff2_w,
    u16* __restrict__ xb, u16* __restrict__ W_in_b,
    u16* __restrict__ qkv_w_b, u16* __restrict__ out_w_b,
    u16* __restrict__ ff1_w_b, u16* __restrict__ ff2_w_b)
{
    const int i = blockIdx.x * 256 + threadIdx.x;   // 0..2392063
    const float* src; u16* dst; int base;
    if (i < 1048576)      { src = x;     dst = xb;      base = 0; }
    else if (i < 1081344) { src = W_in;  dst = W_in_b;  base = 1048576; }
    else if (i < 1277952) { src = qkv_w; dst = qkv_w_b; base = 1081344; }
    else if (i < 1343488) { src = out_w; dst = out_w_b; base = 1277952; }
    else if (i < 1867776) { src = ff1_w; dst = ff1_w_b; base = 1343488; }
    else                  { src = ff2_w; dst = ff2_w_b; base = 1867776; }
    const int e = (i - base) * 4;
    const float4 v = *(const float4*)(src + e);
    ushort4 o;
    o.x = f2bf(v.x); o.y = f2bf(v.y); o.z = f2bf(v.z); o.w = f2bf(v.w);
    *(ushort4*)(dst + e) = o;
}

// ---------------------------------------------------------------------------
// bf16 MFMA GEMM: C[M,N] = A[M,K] @ W[N,K]^T + bias  (m97 structure)
// 128x128 tile, BK=32, 256 thr = 4 waves (2x2), 16 MFMA 16x16x32 per wave/iter.
// global_load_lds width-16 staging; 2-barrier K-loop.
// MODE 1: +posenc, write f32+bf16 | MODE 0: write bf16 | MODE 2: relu, bf16 |
// MODE 3: write f32.
// ---------------------------------------------------------------------------
template <int MODE>
__global__ __launch_bounds__(256) void gemm_mfma(
    const u16* __restrict__ A, const u16* __restrict__ W,
    const float* __restrict__ bias,
    float* __restrict__ Cf, u16* __restrict__ Cb,
    int M, int N, int K)
{
    __shared__ __align__(16) u16 As[128 * 32];
    __shared__ __align__(16) u16 Bs[128 * 32];
    const int t = threadIdx.x;
    const int w = t >> 6, lane = t & 63;
    const int col = lane & 15, quad = lane >> 4;
    const int m0 = blockIdx.x * 128, n0 = blockIdx.y * 128;
    const int wm = (w >> 1) * 64, wn = (w & 1) * 64;

    // staging: lane covers row (seg*16 + lane/4), k-cols (lane%4)*8 .. +7
    const int r0 = lane >> 2;
    const int kc = (lane & 3) * 8;
    const u16* pA0 = A + (size_t)(m0 + (w * 2 + 0) * 16 + r0) * K + kc;
    const u16* pA1 = A + (size_t)(m0 + (w * 2 + 1) * 16 + r0) * K + kc;
    const u16* pB0 = W + (size_t)(n0 + (w * 2 + 0) * 16 + r0) * K + kc;
    const u16* pB1 = W + (size_t)(n0 + (w * 2 + 1) * 16 + r0) * K + kc;
    u16* lA0 = As + (w * 2 + 0) * 512;
    u16* lA1 = As + (w * 2 + 1) * 512;
    u16* lB0 = Bs + (w * 2 + 0) * 512;
    u16* lB1 = Bs + (w * 2 + 1) * 512;

    f32x4v acc[4][4];
#pragma unroll
    for (int i = 0; i < 4; ++i)
#pragma unroll
        for (int j = 0; j < 4; ++j) acc[i][j] = (f32x4v){0.f, 0.f, 0.f, 0.f};

    for (int kb = 0; kb < K; kb += 32) {
        __syncthreads();              // previous tile's readers done
        load_lds16(pA0 + kb, lA0);
        load_lds16(pA1 + kb, lA1);
        load_lds16(pB0 + kb, lB0);
        load_lds16(pB1 + kb, lB1);
        __syncthreads();              // drains vmcnt; LDS tiles ready

        frag8 a[4], b[4];
#pragma unroll
        for (int i = 0; i < 4; ++i)
            a[i] = *(const frag8*)&As[(wm + i * 16 + col) * 32 + quad * 8];
#pragma unroll
        for (int j = 0; j < 4; ++j)
            b[j] = *(const frag8*)&Bs[(wn + j * 16 + col) * 32 + quad * 8];
#pragma unroll
        for (int i = 0; i < 4; ++i)
#pragma unroll
            for (int j = 0; j < 4; ++j)
                acc[i][j] = __builtin_amdgcn_mfma_f32_16x16x32_bf16(
                    a[i], b[j], acc[i][j], 0, 0, 0);
    }

    // epilogue: D[row=quad*4+r][col=lane&15]
#pragma unroll
    for (int j = 0; j < 4; ++j) {
        const int cn = n0 + wn + j * 16 + col;
        const float bv = bias[cn];
#pragma unroll
        for (int i = 0; i < 4; ++i) {
#pragma unroll
            for (int r = 0; r < 4; ++r) {
                const int cm = m0 + wm + i * 16 + quad * 4 + r;
                float v = acc[i][j][r] + bv;
                if (MODE == 1) v += pe_val(cm & (S_LEN - 1), cn);
                if (MODE == 2) v = fmaxf(v, 0.f);
                if (MODE == 1 || MODE == 3) Cf[(size_t)cm * N + cn] = v;
                if (MODE != 3) Cb[(size_t)cm * N + cn] = f2bf(v);
            }
        }
    }
}

// ---------------------------------------------------------------------------
// Flash attention, bf16 in/out (qkv: [NTOK,768] bf16; ctx: [NTOK,256] bf16).
// Same structure as round 2; 1/8 scale applied to S post-MFMA (exact).
// Rows padded to 72 bf16 (144 B) -> near-conflict-free b128 frag reads.
// ---------------------------------------------------------------------------
#define PADW 72
__global__ __launch_bounds__(256) void attn_mfma(const u16* __restrict__ qkv,
                                                 u16* __restrict__ ctx)
{
    __shared__ __align__(16) u16 Ks[64][PADW];
    __shared__ __align__(16) u16 Vt[64][PADW];
    __shared__ __align__(16) u16 Ps[4][16][PADW];

    const int t = threadIdx.x;
    const int w = t >> 6;
    const int lane = t & 63;
    const int col = lane & 15;
    const int quad = lane >> 4;

    const int bh = blockIdx.x;
    const int b = bh >> 2;
    const int hh = bh & 3;
    const int qt = blockIdx.y;

    const int qrow = qt * 64 + w * 16 + col;
    const u16* qp = qkv + (size_t)(b * S_LEN + qrow) * 768 + hh * HDIM;
    frag8 qf[2];
    qf[0] = *(const frag8*)(qp + quad * 8);
    qf[1] = *(const frag8*)(qp + 32 + quad * 8);

    f32x4v Oacc[4];
    float m_r[4], l_r[4];
#pragma unroll
    for (int nt = 0; nt < 4; ++nt) Oacc[nt] = (f32x4v){0.f, 0.f, 0.f, 0.f};
#pragma unroll
    for (int r = 0; r < 4; ++r) { m_r[r] = -1e30f; l_r[r] = 0.f; }

    const int dcol = (t & 15) * 4;
    const int kg = t >> 4;

    for (int kt = 0; kt < S_LEN / 64; ++kt) {
        __syncthreads();
        u16 vr[4][4];
#pragma unroll
        for (int r = 0; r < 4; ++r) {
            const int key = kg * 4 + r;
            const u16* kp = qkv + (size_t)(b * S_LEN + kt * 64 + key) * 768
                            + 256 + hh * HDIM + dcol;
            *(ushort4*)&Ks[key][dcol] = *(const ushort4*)kp;
            const ushort4 vv = *(const ushort4*)(kp + 256);
            vr[r][0] = vv.x; vr[r][1] = vv.y; vr[r][2] = vv.z; vr[r][3] = vv.w;
        }
#pragma unroll
        for (int dd = 0; dd < 4; ++dd) {
            ushort4 o;
            o.x = vr[0][dd]; o.y = vr[1][dd]; o.z = vr[2][dd]; o.w = vr[3][dd];
            *(ushort4*)&Vt[dcol + dd][kg * 4] = o;
        }
        __syncthreads();

        // S = (Q K^T) * 1/8
        f32x4v S[4];
#pragma unroll
        for (int nt = 0; nt < 4; ++nt) {
            const frag8 k0 = *(const frag8*)&Ks[nt * 16 + col][quad * 8];
            const frag8 k1 = *(const frag8*)&Ks[nt * 16 + col][32 + quad * 8];
            f32x4v s = (f32x4v){0.f, 0.f, 0.f, 0.f};
            s = __builtin_amdgcn_mfma_f32_16x16x32_bf16(qf[0], k0, s, 0, 0, 0);
            s = __builtin_amdgcn_mfma_f32_16x16x32_bf16(qf[1], k1, s, 0, 0, 0);
            S[nt] = s * 0.125f;
        }

        // online softmax
        float mt[4];
#pragma unroll
        for (int r = 0; r < 4; ++r) {
            mt[r] = fmaxf(fmaxf(S[0][r], S[1][r]), fmaxf(S[2][r], S[3][r]));
#pragma unroll
            for (int msk = 1; msk < 16; msk <<= 1)
                mt[r] = fmaxf(mt[r], __shfl_xor(mt[r], msk));
        }
        float alpha[4], psum[4];
#pragma unroll
        for (int r = 0; r < 4; ++r) {
            const float mn = fmaxf(m_r[r], mt[r]);
            alpha[r] = __expf(m_r[r] - mn);
            m_r[r] = mn;
            psum[r] = 0.f;
        }
#pragma unroll
        for (int nt = 0; nt < 4; ++nt) {
#pragma unroll
            for (int r = 0; r < 4; ++r) {
                const float p = __expf(S[nt][r] - m_r[r]);
                psum[r] += p;
                Ps[w][quad * 4 + r][nt * 16 + col] = f2bf(p);
            }
        }
#pragma unroll
        for (int r = 0; r < 4; ++r) {
#pragma unroll
            for (int msk = 1; msk < 16; msk <<= 1)
                psum[r] += __shfl_xor(psum[r], msk);
            l_r[r] = l_r[r] * alpha[r] + psum[r];
        }
#pragma unroll
        for (int nt = 0; nt < 4; ++nt) {
#pragma unroll
            for (int r = 0; r < 4; ++r) Oacc[nt][r] *= alpha[r];
        }
        // Ps is wave-private (written+read by same wave): no barrier needed;
        // compiler orders via lgkmcnt. Vt/Ks protected by loop-top barrier.

        const frag8 p0 = *(const frag8*)&Ps[w][col][quad * 8];
        const frag8 p1 = *(const frag8*)&Ps[w][col][32 + quad * 8];
#pragma unroll
        for (int nt = 0; nt < 4; ++nt) {
            const frag8 v0 = *(const frag8*)&Vt[nt * 16 + col][quad * 8];
            const frag8 v1 = *(const frag8*)&Vt[nt * 16 + col][32 + quad * 8];
            Oacc[nt] = __builtin_amdgcn_mfma_f32_16x16x32_bf16(p0, v0, Oacc[nt], 0, 0, 0);
            Oacc[nt] = __builtin_amdgcn_mfma_f32_16x16x32_bf16(p1, v1, Oacc[nt], 0, 0, 0);
        }
    }

    float inv[4];
#pragma unroll
    for (int r = 0; r < 4; ++r) inv[r] = 1.f / l_r[r];
    u16* op = ctx + (size_t)(b * S_LEN + qt * 64 + w * 16) * DMODEL + hh * HDIM;
#pragma unroll
    for (int nt = 0; nt < 4; ++nt) {
#pragma unroll
        for (int r = 0; r < 4; ++r) {
            const int q = quad * 4 + r;
            op[(size_t)q * DMODEL + nt * 16 + col] = f2bf(Oacc[nt][r] * inv[r]);
        }
    }
}

// ---------------------------------------------------------------------------
// h = LayerNorm(h + r); writes fp32 h and bf16 hb
// ---------------------------------------------------------------------------
__global__ __launch_bounds__(256) void add_ln(float* __restrict__ h,
                                              u16* __restrict__ hb,
                                              const float* __restrict__ r,
                                              const float* __restrict__ w,
                                              const float* __restrict__ b)
{
    const int t = blockIdx.x;
    const int d = threadIdx.x;
    const size_t idx = (size_t)t * DMODEL + d;
    const float x = h[idx] + r[idx];

    float s = x, s2 = x * x;
#pragma unroll
    for (int off = 32; off; off >>= 1) {
        s += __shfl_down(s, off);
        s2 += __shfl_down(s2, off);
    }
    __shared__ float ls[4], ls2[4];
    __shared__ float mu_s, rs_s;
    const int wid = d >> 6, lane = d & 63;
    if (lane == 0) { ls[wid] = s; ls2[wid] = s2; }
    __syncthreads();
    if (d == 0) {
        const float ts = ls[0] + ls[1] + ls[2] + ls[3];
        const float ts2 = ls2[0] + ls2[1] + ls2[2] + ls2[3];
        const float mu = ts * (1.f / DMODEL);
        const float var = ts2 * (1.f / DMODEL) - mu * mu;
        mu_s = mu;
        rs_s = rsqrtf(var + EPSV);
    }
    __syncthreads();
    const float y = (x - mu_s) * rs_s * w[d] + b[d];
    h[idx] = y;
    hb[idx] = f2bf(y);
}

__global__ __launch_bounds__(256) void final_proj(const float* __restrict__ h,
                                                  const float* __restrict__ Wfc,
                                                  const float* __restrict__ bfc,
                                                  float* __restrict__ out)
{
    const int idx = blockIdx.x * 256 + threadIdx.x;
    const int b = idx >> 9;
    const int o = idx & 511;
    const float* hp = h + (size_t)(b * S_LEN + S_LEN - 1) * DMODEL;
    const float* wp = Wfc + (size_t)o * DMODEL;
    float s = 0.f;
#pragma unroll 4
    for (int d = 0; d < DMODEL; ++d) s += hp[d] * wp[d];
    out[idx] = s + bfc[o];
}

extern "C" void kernel_launch(void* const* d_in, const int* in_sizes, int n_in,
                              void* d_out, int out_size, void* d_ws, size_t ws_size,
                              hipStream_t stream)
{
    const float* x     = (const float*)d_in[0];
    const float* W_in  = (const float*)d_in[1];
    const float* b_in  = (const float*)d_in[2];
    const float* qkv_w = (const float*)d_in[3];
    const float* qkv_b = (const float*)d_in[4];
    const float* out_w = (const float*)d_in[5];
    const float* out_b = (const float*)d_in[6];
    const float* ln1_w = (const float*)d_in[7];
    const float* ln1_b = (const float*)d_in[8];
    const float* ff1_w = (const float*)d_in[9];
    const float* ff1_b = (const float*)d_in[10];
    const float* ff2_w = (const float*)d_in[11];
    const float* ff2_b = (const float*)d_in[12];
    const float* ln2_w = (const float*)d_in[13];
    const float* ln2_b = (const float*)d_in[14];
    const float* W_fc  = (const float*)d_in[15];
    const float* b_fc  = (const float*)d_in[16];
    float* out = (float*)d_out;

    char* p = (char*)d_ws;
    float* h  = (float*)p; p += (size_t)NTOK * DMODEL * 4;   // 8 MB
    float* sa = (float*)p; p += (size_t)NTOK * DMODEL * 4;   // 8 MB
    u16* hb    = (u16*)p;  p += (size_t)NTOK * DMODEL * 2;   // 4 MB
    u16* xb    = (u16*)p;  p += (size_t)NTOK * INDIM * 2;    // 8 MB
    u16* qkvb  = (u16*)p;  p += (size_t)NTOK * 768 * 2;      // 12 MB
    u16* ctxb  = (u16*)p;  p += (size_t)NTOK * DMODEL * 2;   // 4 MB
    u16* ffb   = (u16*)p;  p += (size_t)NTOK * FFDIM * 2;    // 32 MB
    u16* W_in_b  = (u16*)p; p += (size_t)131072 * 2;
    u16* qkv_w_b = (u16*)p; p += (size_t)786432 * 2;
    u16* out_w_b = (u16*)p; p += (size_t)262144 * 2;
    u16* ff1_w_b = (u16*)p; p += (size_t)2097152 * 2;
    u16* ff2_w_b = (u16*)p; p += (size_t)2097152 * 2;
    if (ws_size < (size_t)90439680) return;

    cvt_all<<<9344, 256, 0, stream>>>(x, W_in, qkv_w, out_w, ff1_w, ff2_w,
                                      xb, W_in_b, qkv_w_b, out_w_b, ff1_w_b, ff2_w_b);

    // input projection + posenc -> h (f32) + hb (bf16)
    gemm_mfma<1><<<dim3(NTOK / 128, DMODEL / 128), 256, 0, stream>>>(
        xb, W_in_b, b_in, h, hb, NTOK, DMODEL, INDIM);

    for (int l = 0; l < NLAYER; ++l) {
        gemm_mfma<0><<<dim3(NTOK / 128, 768 / 128), 256, 0, stream>>>(
            hb, qkv_w_b + (size_t)l * 768 * DMODEL, qkv_b + l * 768,
            nullptr, qkvb, NTOK, 768, DMODEL);
        attn_mfma<<<dim3(BATCH * NHEAD, S_LEN / 64), 256, 0, stream>>>(qkvb, ctxb);
        gemm_mfma<3><<<dim3(NTOK / 128, DMODEL / 128), 256, 0, stream>>>(
            ctxb, out_w_b + (size_t)l * DMODEL * DMODEL, out_b + l * DMODEL,
            sa, nullptr, NTOK, DMODEL, DMODEL);
        add_ln<<<NTOK, 256, 0, stream>>>(h, hb, sa, ln1_w + l * DMODEL, ln1_b + l * DMODEL);
        gemm_mfma<2><<<dim3(NTOK / 128, FFDIM / 128), 256, 0, stream>>>(
            hb, ff1_w_b + (size_t)l * FFDIM * DMODEL, ff1_b + l * FFDIM,
            nullptr, ffb, NTOK, FFDIM, DMODEL);
        gemm_mfma<3><<<dim3(NTOK / 128, DMODEL / 128), 256, 0, stream>>>(
            ffb, ff2_w_b + (size_t)l * DMODEL * FFDIM, ff2_b + l * DMODEL,
            sa, nullptr, NTOK, DMODEL, FFDIM);
        add_ln<<<NTOK, 256, 0, stream>>>(h, hb, sa, ln2_w + l * DMODEL, ln2_b + l * DMODEL);
    }

    final_proj<<<8, 256, 0, stream>>>(h, W_fc, b_fc, out);
}

// Round 4
// 741.070 us; speedup vs baseline: 10.0073x; 1.2015x over previous
//
#include <hip/hip_runtime.h>
#include <math.h>

#define S_LEN 2048
#define DMODEL 256
#define NHEAD 4
#define HDIM 64
#define NLAYER 4
#define FFDIM 2048
#define INDIM 512
#define BATCH 4
#define NTOK (BATCH * S_LEN) /* 8192 */
#define EPSV 1e-5f

typedef __attribute__((ext_vector_type(8))) short frag8;
typedef __attribute__((ext_vector_type(4))) float f32x4v;
typedef unsigned short u16;
typedef unsigned int u32;

// sin/cos positional encoding, matching the JAX reference
__device__ __forceinline__ float pe_val(int s, int d) {
    const float c = 0.035977892f; // ln(10000)/256
    float dv = expf(-(float)(d & ~1) * c);
    float arg = (float)s * dv;
    return (d & 1) ? cosf(arg) : sinf(arg);
}

// fp32 -> bf16 bits, round-to-nearest-even
__device__ __forceinline__ u16 f2bf(float f) {
    union { float f; unsigned u; } v; v.f = f;
    unsigned r = v.u + 0x7fffu + ((v.u >> 16) & 1u);
    return (u16)(r >> 16);
}

// pack two fp32 into (bf16(hi)<<16)|bf16(lo), truncation, single v_perm_b32
__device__ __forceinline__ u32 pk2bf(float lo, float hi) {
    union { float f; u32 u; } a, b; a.f = lo; b.f = hi;
    return __builtin_amdgcn_perm(b.u, a.u, 0x07060302u);
}

// async global->LDS, 16 B per lane; LDS dest = wave-uniform base + lane*16
__device__ __forceinline__ void load_lds16(const u16* g, u16* l) {
    __builtin_amdgcn_global_load_lds(
        (const __attribute__((address_space(1))) unsigned int*)g,
        (__attribute__((address_space(3))) unsigned int*)l, 16, 0, 0);
}

// ---------------------------------------------------------------------------
// Convert x + all layer weights fp32 -> bf16 (one launch, float4 granules).
// ---------------------------------------------------------------------------
__global__ __launch_bounds__(256) void cvt_all(
    const float* __restrict__ x, const float* __restrict__ W_in,
    const float* __restrict__ qkv_w, const float* __restrict__ out_w,
    const float* __restrict__ ff1_w, const float* __restrict__ ff2_w,
    u16* __restrict__ xb, u16* __restrict__ W_in_b,
    u16* __restrict__ qkv_w_b, u16* __restrict__ out_w_b,
    u16* __restrict__ ff1_w_b, u16* __restrict__ ff2_w_b)
{
    const int i = blockIdx.x * 256 + threadIdx.x;   // 0..2392063
    const float* src; u16* dst; int base;
    if (i < 1048576)      { src = x;     dst = xb;      base = 0; }
    else if (i < 1081344) { src = W_in;  dst = W_in_b;  base = 1048576; }
    else if (i < 1277952) { src = qkv_w; dst = qkv_w_b; base = 1081344; }
    else if (i < 1343488) { src = out_w; dst = out_w_b; base = 1277952; }
    else if (i < 1867776) { src = ff1_w; dst = ff1_w_b; base = 1343488; }
    else                  { src = ff2_w; dst = ff2_w_b; base = 1867776; }
    const int e = (i - base) * 4;
    const float4 v = *(const float4*)(src + e);
    ushort4 o;
    o.x = f2bf(v.x); o.y = f2bf(v.y); o.z = f2bf(v.z); o.w = f2bf(v.w);
    *(ushort4*)(dst + e) = o;
}

// ---------------------------------------------------------------------------
// bf16 MFMA GEMM: C[M,N] = A[M,K] @ W[N,K]^T + bias  (m97 structure)
// BM x 128 tile (BM=128 or 64), BK=32, 256 thr = 4 waves (2x2).
// MODE 1: +posenc, f32+bf16 | 0: bf16 | 2: relu bf16 | 3: f32.
// ---------------------------------------------------------------------------
template <int MODE, int BM>
__global__ __launch_bounds__(256) void gemm_mfma(
    const u16* __restrict__ A, const u16* __restrict__ W,
    const float* __restrict__ bias,
    float* __restrict__ Cf, u16* __restrict__ Cb,
    int M, int N, int K)
{
    constexpr int NI = BM / 32;            // M-frags per wave (128->4, 64->2)
    __shared__ __align__(16) u16 As[BM * 32];
    __shared__ __align__(16) u16 Bs[128 * 32];
    const int t = threadIdx.x;
    const int w = t >> 6, lane = t & 63;
    const int col = lane & 15, quad = lane >> 4;
    const int m0 = blockIdx.x * BM, n0 = blockIdx.y * 128;
    const int wm = (w >> 1) * (BM / 2), wn = (w & 1) * 64;

    const int r0 = lane >> 2;
    const int kc = (lane & 3) * 8;
    // A staging: BM=128: wave stages rows w*32..w*32+31 (2 loads);
    //            BM=64 : wave stages rows w*16..w*16+15 (1 load).
    const u16* pA0 = A + (size_t)(m0 + (BM == 128 ? (w * 2 + 0) * 16 : w * 16) + r0) * K + kc;
    const u16* pA1 = A + (size_t)(m0 + (w * 2 + 1) * 16 + r0) * K + kc;  // BM=128 only
    const u16* pB0 = W + (size_t)(n0 + (w * 2 + 0) * 16 + r0) * K + kc;
    const u16* pB1 = W + (size_t)(n0 + (w * 2 + 1) * 16 + r0) * K + kc;
    u16* lA0 = As + (BM == 128 ? (w * 2 + 0) * 512 : w * 512);
    u16* lA1 = As + (w * 2 + 1) * 512;
    u16* lB0 = Bs + (w * 2 + 0) * 512;
    u16* lB1 = Bs + (w * 2 + 1) * 512;

    f32x4v acc[NI][4];
#pragma unroll
    for (int i = 0; i < NI; ++i)
#pragma unroll
        for (int j = 0; j < 4; ++j) acc[i][j] = (f32x4v){0.f, 0.f, 0.f, 0.f};

    for (int kb = 0; kb < K; kb += 32) {
        __syncthreads();
        load_lds16(pA0 + kb, lA0);
        if (BM == 128) load_lds16(pA1 + kb, lA1);
        load_lds16(pB0 + kb, lB0);
        load_lds16(pB1 + kb, lB1);
        __syncthreads();

        frag8 a[NI], b[4];
#pragma unroll
        for (int i = 0; i < NI; ++i)
            a[i] = *(const frag8*)&As[(wm + i * 16 + col) * 32 + quad * 8];
#pragma unroll
        for (int j = 0; j < 4; ++j)
            b[j] = *(const frag8*)&Bs[(wn + j * 16 + col) * 32 + quad * 8];
#pragma unroll
        for (int i = 0; i < NI; ++i)
#pragma unroll
            for (int j = 0; j < 4; ++j)
                acc[i][j] = __builtin_amdgcn_mfma_f32_16x16x32_bf16(
                    a[i], b[j], acc[i][j], 0, 0, 0);
    }

#pragma unroll
    for (int j = 0; j < 4; ++j) {
        const int cn = n0 + wn + j * 16 + col;
        const float bv = bias[cn];
#pragma unroll
        for (int i = 0; i < NI; ++i) {
#pragma unroll
            for (int r = 0; r < 4; ++r) {
                const int cm = m0 + wm + i * 16 + quad * 4 + r;
                float v = acc[i][j][r] + bv;
                if (MODE == 1) v += pe_val(cm & (S_LEN - 1), cn);
                if (MODE == 2) v = fmaxf(v, 0.f);
                if (MODE == 1 || MODE == 3) Cf[(size_t)cm * N + cn] = v;
                if (MODE != 3) Cb[(size_t)cm * N + cn] = f2bf(v);
            }
        }
    }
}

// ---------------------------------------------------------------------------
// vt_prep: per layer, transpose V out of qkv into vt[bh][d][s] (bf16).
// Grid (16 bh, 32 s-tiles), 256 thr; LDS-tiled 64x64 transpose.
// ---------------------------------------------------------------------------
#define PADW 72
__global__ __launch_bounds__(256) void vt_prep(const u16* __restrict__ qkv,
                                               u16* __restrict__ vt)
{
    __shared__ __align__(16) u16 Vl[64][PADW];
    const int t = threadIdx.x;
    const int bh = blockIdx.x, b = bh >> 2, hh = bh & 3;
    const int st = blockIdx.y;
    {
        const int row = t >> 2, seg = (t & 3) * 16;
        const u16* src = qkv + (size_t)(b * S_LEN + st * 64 + row) * 768
                         + 512 + hh * HDIM + seg;
        *(frag8*)&Vl[row][seg]     = *(const frag8*)src;
        *(frag8*)&Vl[row][seg + 8] = *(const frag8*)(src + 8);
    }
    __syncthreads();
    const int d = t >> 2, s0 = (t & 3) * 16;
    frag8 v0, v1;
#pragma unroll
    for (int i = 0; i < 8; ++i) v0[i] = (short)Vl[s0 + i][d];
#pragma unroll
    for (int i = 0; i < 8; ++i) v1[i] = (short)Vl[s0 + 8 + i][d];
    u16* dst = vt + ((size_t)bh * 64 + d) * S_LEN + st * 64 + s0;
    *(frag8*)dst = v0;
    *(frag8*)(dst + 8) = v1;
}

// ---------------------------------------------------------------------------
// Flash attention, transposed-S formulation (bf16 MFMA 16x16x32).
// Block = 4 waves, 64 queries; each lane owns ONE query (col), softmax state
// is lane-scalar (dup x4 over quad); S^T = K Q^T, O^T = V^T P^T.
// K staged from qkv, V^T staged from vt (pre-transposed). P packed to bf16
// pairs via v_perm and stored [q][key]-major (B-frag layout for PV).
// ---------------------------------------------------------------------------
__global__ __launch_bounds__(256) void attn_mfma(const u16* __restrict__ qkv,
                                                 const u16* __restrict__ vt,
                                                 u16* __restrict__ ctx)
{
    __shared__ __align__(16) u16 Ks[64][PADW];
    __shared__ __align__(16) u16 Vt[64][PADW];
    __shared__ __align__(16) u16 Ps[4][16][PADW];

    const int t = threadIdx.x;
    const int w = t >> 6, lane = t & 63;
    const int col = lane & 15, quad = lane >> 4;
    const int bh = blockIdx.x, b = bh >> 2, hh = bh & 3;
    const int qt = blockIdx.y;

    // Q as B-operand: lane holds Q[q=col][dim=quad*8+j] (two 32-dim halves)
    const int qrow = qt * 64 + w * 16 + col;
    const u16* qp = qkv + (size_t)(b * S_LEN + qrow) * 768 + hh * HDIM;
    const frag8 qf0 = *(const frag8*)(qp + quad * 8);
    const frag8 qf1 = *(const frag8*)(qp + 32 + quad * 8);

    f32x4v Oacc[4];   // O^T: D[d=dt*16+quad*4+r][q=col]
#pragma unroll
    for (int dt = 0; dt < 4; ++dt) Oacc[dt] = (f32x4v){0.f, 0.f, 0.f, 0.f};
    float m_r = -1e30f, l_r = 0.f;   // per-query scalars (raw-score domain)

    const float SCL = 0.125f * 1.44269504f;  // log2(e)/8

    // staging map: thread -> (row = t>>2, 16-col seg = t&3)
    const int srow = t >> 2, scol = (t & 3) * 16;
    const u16* kbase = qkv + (size_t)(b * S_LEN + srow) * 768 + 256 + hh * HDIM + scol;
    const u16* vbase = vt + ((size_t)bh * 64 + srow) * S_LEN + scol;

    for (int kt = 0; kt < S_LEN / 64; ++kt) {
        __syncthreads();
        {
            const u16* kp = kbase + (size_t)kt * 64 * 768;
            const u16* vp = vbase + kt * 64;
            *(frag8*)&Ks[srow][scol]     = *(const frag8*)kp;
            *(frag8*)&Ks[srow][scol + 8] = *(const frag8*)(kp + 8);
            *(frag8*)&Vt[srow][scol]     = *(const frag8*)vp;
            *(frag8*)&Vt[srow][scol + 8] = *(const frag8*)(vp + 8);
        }
        __syncthreads();

        // ---- S^T = K Q^T : lane gets keys nt*16+quad*4+r for its q=col ----
        f32x4v S[4];
#pragma unroll
        for (int nt = 0; nt < 4; ++nt) {
            const frag8 k0 = *(const frag8*)&Ks[nt * 16 + col][quad * 8];
            const frag8 k1 = *(const frag8*)&Ks[nt * 16 + col][32 + quad * 8];
            f32x4v s = (f32x4v){0.f, 0.f, 0.f, 0.f};
            s = __builtin_amdgcn_mfma_f32_16x16x32_bf16(k0, qf0, s, 0, 0, 0);
            s = __builtin_amdgcn_mfma_f32_16x16x32_bf16(k1, qf1, s, 0, 0, 0);
            S[nt] = s;
        }

        // ---- online softmax, lane-local + 2 cross-quad shuffles ----
        float mt = -1e30f;
#pragma unroll
        for (int nt = 0; nt < 4; ++nt) {
            mt = fmaxf(mt, fmaxf(fmaxf(S[nt][0], S[nt][1]),
                                 fmaxf(S[nt][2], S[nt][3])));
        }
        mt = fmaxf(mt, __shfl_xor(mt, 16));
        mt = fmaxf(mt, __shfl_xor(mt, 32));
        const float mn = fmaxf(m_r, mt);
        const float alpha = exp2f((m_r - mn) * SCL);
        m_r = mn;
        const float mk = mn * SCL;
        float psum = 0.f;
#pragma unroll
        for (int nt = 0; nt < 4; ++nt) {
            float p0 = exp2f(S[nt][0] * SCL - mk);
            float p1 = exp2f(S[nt][1] * SCL - mk);
            float p2 = exp2f(S[nt][2] * SCL - mk);
            float p3 = exp2f(S[nt][3] * SCL - mk);
            psum += (p0 + p1) + (p2 + p3);
            uint2 pk;
            pk.x = pk2bf(p0, p1);
            pk.y = pk2bf(p2, p3);
            *(uint2*)&Ps[w][col][nt * 16 + quad * 4] = pk;
        }
        psum += __shfl_xor(psum, 16);
        psum += __shfl_xor(psum, 32);
        l_r = l_r * alpha + psum;
#pragma unroll
        for (int dt = 0; dt < 4; ++dt) Oacc[dt] *= alpha;

        // ---- O^T += V^T P^T (Ps is wave-private: lgkmcnt ordering suffices) ----
        const frag8 p0 = *(const frag8*)&Ps[w][col][quad * 8];
        const frag8 p1 = *(const frag8*)&Ps[w][col][32 + quad * 8];
#pragma unroll
        for (int dt = 0; dt < 4; ++dt) {
            const frag8 v0 = *(const frag8*)&Vt[dt * 16 + col][quad * 8];
            const frag8 v1 = *(const frag8*)&Vt[dt * 16 + col][32 + quad * 8];
            Oacc[dt] = __builtin_amdgcn_mfma_f32_16x16x32_bf16(v0, p0, Oacc[dt], 0, 0, 0);
            Oacc[dt] = __builtin_amdgcn_mfma_f32_16x16x32_bf16(v1, p1, Oacc[dt], 0, 0, 0);
        }
    }

    // ---- epilogue: ctx[q][hh*64+d] = O^T[d][q] / l ----
    const float inv = 1.f / l_r;
    u16* op = ctx + (size_t)(b * S_LEN + qrow) * DMODEL + hh * HDIM;
#pragma unroll
    for (int dt = 0; dt < 4; ++dt) {
        ushort4 o;
        o.x = f2bf(Oacc[dt][0] * inv);
        o.y = f2bf(Oacc[dt][1] * inv);
        o.z = f2bf(Oacc[dt][2] * inv);
        o.w = f2bf(Oacc[dt][3] * inv);
        *(ushort4*)(op + dt * 16 + quad * 4) = o;
    }
}

// ---------------------------------------------------------------------------
// h = LayerNorm(h + r); writes fp32 h and bf16 hb
// ---------------------------------------------------------------------------
__global__ __launch_bounds__(256) void add_ln(float* __restrict__ h,
                                              u16* __restrict__ hb,
                                              const float* __restrict__ r,
                                              const float* __restrict__ w,
                                              const float* __restrict__ b)
{
    const int t = blockIdx.x;
    const int d = threadIdx.x;
    const size_t idx = (size_t)t * DMODEL + d;
    const float x = h[idx] + r[idx];

    float s = x, s2 = x * x;
#pragma unroll
    for (int off = 32; off; off >>= 1) {
        s += __shfl_down(s, off);
        s2 += __shfl_down(s2, off);
    }
    __shared__ float ls[4], ls2[4];
    __shared__ float mu_s, rs_s;
    const int wid = d >> 6, lane = d & 63;
    if (lane == 0) { ls[wid] = s; ls2[wid] = s2; }
    __syncthreads();
    if (d == 0) {
        const float ts = ls[0] + ls[1] + ls[2] + ls[3];
        const float ts2 = ls2[0] + ls2[1] + ls2[2] + ls2[3];
        const float mu = ts * (1.f / DMODEL);
        const float var = ts2 * (1.f / DMODEL) - mu * mu;
        mu_s = mu;
        rs_s = rsqrtf(var + EPSV);
    }
    __syncthreads();
    const float y = (x - mu_s) * rs_s * w[d] + b[d];
    h[idx] = y;
    hb[idx] = f2bf(y);
}

__global__ __launch_bounds__(256) void final_proj(const float* __restrict__ h,
                                                  const float* __restrict__ Wfc,
                                                  const float* __restrict__ bfc,
                                                  float* __restrict__ out)
{
    const int idx = blockIdx.x * 256 + threadIdx.x;
    const int b = idx >> 9;
    const int o = idx & 511;
    const float* hp = h + (size_t)(b * S_LEN + S_LEN - 1) * DMODEL;
    const float* wp = Wfc + (size_t)o * DMODEL;
    float s = 0.f;
#pragma unroll 4
    for (int d = 0; d < DMODEL; ++d) s += hp[d] * wp[d];
    out[idx] = s + bfc[o];
}

extern "C" void kernel_launch(void* const* d_in, const int* in_sizes, int n_in,
                              void* d_out, int out_size, void* d_ws, size_t ws_size,
                              hipStream_t stream)
{
    const float* x     = (const float*)d_in[0];
    const float* W_in  = (const float*)d_in[1];
    const float* b_in  = (const float*)d_in[2];
    const float* qkv_w = (const float*)d_in[3];
    const float* qkv_b = (const float*)d_in[4];
    const float* out_w = (const float*)d_in[5];
    const float* out_b = (const float*)d_in[6];
    const float* ln1_w = (const float*)d_in[7];
    const float* ln1_b = (const float*)d_in[8];
    const float* ff1_w = (const float*)d_in[9];
    const float* ff1_b = (const float*)d_in[10];
    const float* ff2_w = (const float*)d_in[11];
    const float* ff2_b = (const float*)d_in[12];
    const float* ln2_w = (const float*)d_in[13];
    const float* ln2_b = (const float*)d_in[14];
    const float* W_fc  = (const float*)d_in[15];
    const float* b_fc  = (const float*)d_in[16];
    float* out = (float*)d_out;

    char* p = (char*)d_ws;
    float* h  = (float*)p; p += (size_t)NTOK * DMODEL * 4;   // 8 MB
    float* sa = (float*)p; p += (size_t)NTOK * DMODEL * 4;   // 8 MB
    u16* hb    = (u16*)p;  p += (size_t)NTOK * DMODEL * 2;   // 4 MB
    u16* xb    = (u16*)p;  p += (size_t)NTOK * INDIM * 2;    // 8 MB
    u16* qkvb  = (u16*)p;  p += (size_t)NTOK * 768 * 2;      // 12 MB
    u16* ctxb  = (u16*)p;  p += (size_t)NTOK * DMODEL * 2;   // 4 MB
    u16* ffb   = (u16*)p;  p += (size_t)NTOK * FFDIM * 2;    // 32 MB
    u16* vtb   = (u16*)p;  p += (size_t)16 * 64 * S_LEN * 2; // 4 MB
    u16* W_in_b  = (u16*)p; p += (size_t)131072 * 2;
    u16* qkv_w_b = (u16*)p; p += (size_t)786432 * 2;
    u16* out_w_b = (u16*)p; p += (size_t)262144 * 2;
    u16* ff1_w_b = (u16*)p; p += (size_t)2097152 * 2;
    u16* ff2_w_b = (u16*)p; p += (size_t)2097152 * 2;
    if (ws_size < (size_t)94633984) return;

    cvt_all<<<9344, 256, 0, stream>>>(x, W_in, qkv_w, out_w, ff1_w, ff2_w,
                                      xb, W_in_b, qkv_w_b, out_w_b, ff1_w_b, ff2_w_b);

    // input projection + posenc -> h (f32) + hb (bf16)
    gemm_mfma<1, 64><<<dim3(NTOK / 64, 2), 256, 0, stream>>>(
        xb, W_in_b, b_in, h, hb, NTOK, DMODEL, INDIM);

    for (int l = 0; l < NLAYER; ++l) {
        gemm_mfma<0, 128><<<dim3(NTOK / 128, 6), 256, 0, stream>>>(
            hb, qkv_w_b + (size_t)l * 768 * DMODEL, qkv_b + l * 768,
            nullptr, qkvb, NTOK, 768, DMODEL);
        vt_prep<<<dim3(16, 32), 256, 0, stream>>>(qkvb, vtb);
        attn_mfma<<<dim3(BATCH * NHEAD, S_LEN / 64), 256, 0, stream>>>(qkvb, vtb, ctxb);
        gemm_mfma<3, 64><<<dim3(NTOK / 64, 2), 256, 0, stream>>>(
            ctxb, out_w_b + (size_t)l * DMODEL * DMODEL, out_b + l * DMODEL,
            sa, nullptr, NTOK, DMODEL, DMODEL);
        add_ln<<<NTOK, 256, 0, stream>>>(h, hb, sa, ln1_w + l * DMODEL, ln1_b + l * DMODEL);
        gemm_mfma<2, 128><<<dim3(NTOK / 128, 16), 256, 0, stream>>>(
            hb, ff1_w_b + (size_t)l * FFDIM * DMODEL, ff1_b + l * FFDIM,
            nullptr, ffb, NTOK, FFDIM, DMODEL);
        gemm_mfma<3, 64><<<dim3(NTOK / 64, 2), 256, 0, stream>>>(
            ffb, ff2_w_b + (size_t)l * DMODEL * FFDIM, ff2_b + l * DMODEL,
            sa, nullptr, NTOK, DMODEL, FFDIM);
        add_ln<<<NTOK, 256, 0, stream>>>(h, hb, sa, ln2_w + l * DMODEL, ln2_b + l * DMODEL);
    }

    final_proj<<<8, 256, 0, stream>>>(h, W_fc, b_fc, out);
}

// Round 5
// 681.810 us; speedup vs baseline: 10.8771x; 1.0869x over previous
//
#include <hip/hip_runtime.h>
#include <math.h>

#define S_LEN 2048
#define DMODEL 256
#define NHEAD 4
#define HDIM 64
#define NLAYER 4
#define FFDIM 2048
#define INDIM 512
#define BATCH 4
#define NTOK (BATCH * S_LEN) /* 8192 */
#define EPSV 1e-5f
#define KSPLIT 4

typedef __attribute__((ext_vector_type(8))) short frag8;
typedef __attribute__((ext_vector_type(4))) float f32x4v;
typedef unsigned short u16;
typedef unsigned int u32;

// sin/cos positional encoding, matching the JAX reference
__device__ __forceinline__ float pe_val(int s, int d) {
    const float c = 0.035977892f; // ln(10000)/256
    float dv = expf(-(float)(d & ~1) * c);
    float arg = (float)s * dv;
    return (d & 1) ? cosf(arg) : sinf(arg);
}

// fp32 -> bf16 bits, round-to-nearest-even
__device__ __forceinline__ u16 f2bf(float f) {
    union { float f; unsigned u; } v; v.f = f;
    unsigned r = v.u + 0x7fffu + ((v.u >> 16) & 1u);
    return (u16)(r >> 16);
}

// pack two fp32 into (bf16(hi)<<16)|bf16(lo), truncation, single v_perm_b32
__device__ __forceinline__ u32 pk2bf(float lo, float hi) {
    union { float f; u32 u; } a, b; a.f = lo; b.f = hi;
    return __builtin_amdgcn_perm(b.u, a.u, 0x07060302u);
}

// async global->LDS, 16 B per lane; LDS dest = wave-uniform base + lane*16
__device__ __forceinline__ void load_lds16(const u16* g, u16* l) {
    __builtin_amdgcn_global_load_lds(
        (const __attribute__((address_space(1))) unsigned int*)g,
        (__attribute__((address_space(3))) unsigned int*)l, 16, 0, 0);
}

// ---------------------------------------------------------------------------
// Convert x + all layer weights fp32 -> bf16 (one launch, float4 granules).
// ---------------------------------------------------------------------------
__global__ __launch_bounds__(256) void cvt_all(
    const float* __restrict__ x, const float* __restrict__ W_in,
    const float* __restrict__ qkv_w, const float* __restrict__ out_w,
    const float* __restrict__ ff1_w, const float* __restrict__ ff2_w,
    u16* __restrict__ xb, u16* __restrict__ W_in_b,
    u16* __restrict__ qkv_w_b, u16* __restrict__ out_w_b,
    u16* __restrict__ ff1_w_b, u16* __restrict__ ff2_w_b)
{
    const int i = blockIdx.x * 256 + threadIdx.x;   // 0..2392063
    const float* src; u16* dst; int base;
    if (i < 1048576)      { src = x;     dst = xb;      base = 0; }
    else if (i < 1081344) { src = W_in;  dst = W_in_b;  base = 1048576; }
    else if (i < 1277952) { src = qkv_w; dst = qkv_w_b; base = 1081344; }
    else if (i < 1343488) { src = out_w; dst = out_w_b; base = 1277952; }
    else if (i < 1867776) { src = ff1_w; dst = ff1_w_b; base = 1343488; }
    else                  { src = ff2_w; dst = ff2_w_b; base = 1867776; }
    const int e = (i - base) * 4;
    const float4 v = *(const float4*)(src + e);
    ushort4 o;
    o.x = f2bf(v.x); o.y = f2bf(v.y); o.z = f2bf(v.z); o.w = f2bf(v.w);
    *(ushort4*)(dst + e) = o;
}

// ---------------------------------------------------------------------------
// bf16 MFMA GEMM, 128x128 tile (m97): C = A @ W^T + bias.
// MODE 0: bf16 out | MODE 2: relu, bf16 out.
// ---------------------------------------------------------------------------
template <int MODE>
__global__ __launch_bounds__(256) void gemm_mfma(
    const u16* __restrict__ A, const u16* __restrict__ W,
    const float* __restrict__ bias, u16* __restrict__ Cb,
    int M, int N, int K)
{
    __shared__ __align__(16) u16 As[128 * 32];
    __shared__ __align__(16) u16 Bs[128 * 32];
    const int t = threadIdx.x;
    const int w = t >> 6, lane = t & 63;
    const int col = lane & 15, quad = lane >> 4;
    const int m0 = blockIdx.x * 128, n0 = blockIdx.y * 128;
    const int wm = (w >> 1) * 64, wn = (w & 1) * 64;

    const int r0 = lane >> 2;
    const int kc = (lane & 3) * 8;
    const u16* pA0 = A + (size_t)(m0 + (w * 2 + 0) * 16 + r0) * K + kc;
    const u16* pA1 = A + (size_t)(m0 + (w * 2 + 1) * 16 + r0) * K + kc;
    const u16* pB0 = W + (size_t)(n0 + (w * 2 + 0) * 16 + r0) * K + kc;
    const u16* pB1 = W + (size_t)(n0 + (w * 2 + 1) * 16 + r0) * K + kc;
    u16* lA0 = As + (w * 2 + 0) * 512;
    u16* lA1 = As + (w * 2 + 1) * 512;
    u16* lB0 = Bs + (w * 2 + 0) * 512;
    u16* lB1 = Bs + (w * 2 + 1) * 512;

    f32x4v acc[4][4];
#pragma unroll
    for (int i = 0; i < 4; ++i)
#pragma unroll
        for (int j = 0; j < 4; ++j) acc[i][j] = (f32x4v){0.f, 0.f, 0.f, 0.f};

    for (int kb = 0; kb < K; kb += 32) {
        __syncthreads();
        load_lds16(pA0 + kb, lA0);
        load_lds16(pA1 + kb, lA1);
        load_lds16(pB0 + kb, lB0);
        load_lds16(pB1 + kb, lB1);
        __syncthreads();

        frag8 a[4], b[4];
#pragma unroll
        for (int i = 0; i < 4; ++i)
            a[i] = *(const frag8*)&As[(wm + i * 16 + col) * 32 + quad * 8];
#pragma unroll
        for (int j = 0; j < 4; ++j)
            b[j] = *(const frag8*)&Bs[(wn + j * 16 + col) * 32 + quad * 8];
#pragma unroll
        for (int i = 0; i < 4; ++i)
#pragma unroll
            for (int j = 0; j < 4; ++j)
                acc[i][j] = __builtin_amdgcn_mfma_f32_16x16x32_bf16(
                    a[i], b[j], acc[i][j], 0, 0, 0);
    }

#pragma unroll
    for (int j = 0; j < 4; ++j) {
        const int cn = n0 + wn + j * 16 + col;
        const float bv = bias[cn];
#pragma unroll
        for (int i = 0; i < 4; ++i) {
#pragma unroll
            for (int r = 0; r < 4; ++r) {
                const int cm = m0 + wm + i * 16 + quad * 4 + r;
                float v = acc[i][j][r] + bv;
                if (MODE == 2) v = fmaxf(v, 0.f);
                Cb[(size_t)cm * N + cn] = f2bf(v);
            }
        }
    }
}

// ---------------------------------------------------------------------------
// bf16 MFMA GEMM, 64x64 tile for N=256 shapes (2 blocks/CU at M=8192,N=256).
// MODE 1: +posenc, writes f32 + bf16 | MODE 3: writes f32 only.
// ---------------------------------------------------------------------------
template <int MODE>
__global__ __launch_bounds__(256) void gemm64(
    const u16* __restrict__ A, const u16* __restrict__ W,
    const float* __restrict__ bias,
    float* __restrict__ Cf, u16* __restrict__ Cb,
    int M, int N, int K)
{
    __shared__ __align__(16) u16 As[64 * 32];
    __shared__ __align__(16) u16 Bs[64 * 32];
    const int t = threadIdx.x;
    const int w = t >> 6, lane = t & 63;
    const int col = lane & 15, quad = lane >> 4;
    const int m0 = blockIdx.x * 64, n0 = blockIdx.y * 64;
    const int wm = (w >> 1) * 32, wn = (w & 1) * 32;

    const int r0 = lane >> 2;
    const int kc = (lane & 3) * 8;
    const u16* pA = A + (size_t)(m0 + w * 16 + r0) * K + kc;
    const u16* pB = W + (size_t)(n0 + w * 16 + r0) * K + kc;
    u16* lA = As + w * 512;
    u16* lB = Bs + w * 512;

    f32x4v acc[2][2];
#pragma unroll
    for (int i = 0; i < 2; ++i)
#pragma unroll
        for (int j = 0; j < 2; ++j) acc[i][j] = (f32x4v){0.f, 0.f, 0.f, 0.f};

    for (int kb = 0; kb < K; kb += 32) {
        __syncthreads();
        load_lds16(pA + kb, lA);
        load_lds16(pB + kb, lB);
        __syncthreads();

        frag8 a[2], b[2];
#pragma unroll
        for (int i = 0; i < 2; ++i)
            a[i] = *(const frag8*)&As[(wm + i * 16 + col) * 32 + quad * 8];
#pragma unroll
        for (int j = 0; j < 2; ++j)
            b[j] = *(const frag8*)&Bs[(wn + j * 16 + col) * 32 + quad * 8];
#pragma unroll
        for (int i = 0; i < 2; ++i)
#pragma unroll
            for (int j = 0; j < 2; ++j)
                acc[i][j] = __builtin_amdgcn_mfma_f32_16x16x32_bf16(
                    a[i], b[j], acc[i][j], 0, 0, 0);
    }

#pragma unroll
    for (int j = 0; j < 2; ++j) {
        const int cn = n0 + wn + j * 16 + col;
        const float bv = bias[cn];
#pragma unroll
        for (int i = 0; i < 2; ++i) {
#pragma unroll
            for (int r = 0; r < 4; ++r) {
                const int cm = m0 + wm + i * 16 + quad * 4 + r;
                float v = acc[i][j][r] + bv;
                if (MODE == 1) v += pe_val(cm & (S_LEN - 1), cn);
                Cf[(size_t)cm * N + cn] = v;
                if (MODE == 1) Cb[(size_t)cm * N + cn] = f2bf(v);
            }
        }
    }
}

// ---------------------------------------------------------------------------
// vt_prep: per layer, transpose V out of qkv into vt[bh][d][s] (bf16).
// ---------------------------------------------------------------------------
#define PADW 72
__global__ __launch_bounds__(256) void vt_prep(const u16* __restrict__ qkv,
                                               u16* __restrict__ vt)
{
    __shared__ __align__(16) u16 Vl[64][PADW];
    const int t = threadIdx.x;
    const int bh = blockIdx.x, b = bh >> 2, hh = bh & 3;
    const int st = blockIdx.y;
    {
        const int row = t >> 2, seg = (t & 3) * 16;
        const u16* src = qkv + (size_t)(b * S_LEN + st * 64 + row) * 768
                         + 512 + hh * HDIM + seg;
        *(frag8*)&Vl[row][seg]     = *(const frag8*)src;
        *(frag8*)&Vl[row][seg + 8] = *(const frag8*)(src + 8);
    }
    __syncthreads();
    const int d = t >> 2, s0 = (t & 3) * 16;
    frag8 v0, v1;
#pragma unroll
    for (int i = 0; i < 8; ++i) v0[i] = (short)Vl[s0 + i][d];
#pragma unroll
    for (int i = 0; i < 8; ++i) v1[i] = (short)Vl[s0 + 8 + i][d];
    u16* dst = vt + ((size_t)bh * 64 + d) * S_LEN + st * 64 + s0;
    *(frag8*)dst = v0;
    *(frag8*)(dst + 8) = v1;
}

// ---------------------------------------------------------------------------
// Flash attention, K-split partial pass. No-max softmax (scores ~ +-1 for
// this model; exp2 overflow needs |s|>800): p = exp2(s * scl), partial
// (O, l) over this block's 512 keys combine LINEARLY across splits.
// S^T = K Q^T, O^T = V^T P^T. All LDS tiles are unpadded [64][32]-u16 chunks
// (GEMM-proven low-conflict) staged via global_load_lds.
// ---------------------------------------------------------------------------
__global__ __launch_bounds__(256) void attn_part(const u16* __restrict__ qkv,
                                                 const u16* __restrict__ vt,
                                                 float* __restrict__ Opart,
                                                 float* __restrict__ lpart)
{
    __shared__ __align__(16) u16 Ks0[64 * 32], Ks1[64 * 32];
    __shared__ __align__(16) u16 Vt0[64 * 32], Vt1[64 * 32];
    __shared__ __align__(16) u16 Ps[4][2][16 * 32];

    const int t = threadIdx.x;
    const int w = t >> 6, lane = t & 63;
    const int col = lane & 15, quad = lane >> 4;
    const int bh = blockIdx.x, b = bh >> 2, hh = bh & 3;
    const int qt = blockIdx.y, ks = blockIdx.z;

    // Q as B-operand: lane holds Q[q=col][dim = chunk*32 + quad*8 + j]
    const int qrow = qt * 64 + w * 16 + col;
    const u16* qp = qkv + (size_t)(b * S_LEN + qrow) * 768 + hh * HDIM;
    const frag8 qf0 = *(const frag8*)(qp + quad * 8);
    const frag8 qf1 = *(const frag8*)(qp + 32 + quad * 8);

    f32x4v Oacc[4];
#pragma unroll
    for (int dt = 0; dt < 4; ++dt) Oacc[dt] = (f32x4v){0.f, 0.f, 0.f, 0.f};
    float lsum = 0.f;
    const float SCL = 0.125f * 1.44269504f;  // log2(e)/8

    // staging: lane i covers row w*16 + i/4, 8-elem seg (i%4)*8 (16 B)
    const int srow = w * 16 + (lane >> 2);
    const int sseg = (lane & 3) * 8;
    const int kb0 = ks * (S_LEN / KSPLIT);
    const u16* kbase = qkv + (size_t)(b * S_LEN + kb0 + srow) * 768
                       + 256 + hh * HDIM + sseg;
    const u16* vbase = vt + ((size_t)bh * 64 + srow) * S_LEN + kb0 + sseg;
    u16* lK0 = Ks0 + w * 512;
    u16* lK1 = Ks1 + w * 512;
    u16* lV0 = Vt0 + w * 512;
    u16* lV1 = Vt1 + w * 512;

    for (int kt = 0; kt < S_LEN / KSPLIT / 64; ++kt) {   // 8 tiles
        __syncthreads();
        const u16* kp = kbase + (size_t)kt * 64 * 768;
        const u16* vp = vbase + kt * 64;
        load_lds16(kp, lK0);        // K dims 0..31
        load_lds16(kp + 32, lK1);   // K dims 32..63
        load_lds16(vp, lV0);        // V^T keys 0..31
        load_lds16(vp + 32, lV1);   // V^T keys 32..63
        __syncthreads();

        // ---- S^T = K Q^T: lane gets keys nt*16 + quad*4 + r for q=col ----
#pragma unroll
        for (int nt = 0; nt < 4; ++nt) {
            const frag8 k0 = *(const frag8*)&Ks0[(nt * 16 + col) * 32 + quad * 8];
            const frag8 k1 = *(const frag8*)&Ks1[(nt * 16 + col) * 32 + quad * 8];
            f32x4v s = (f32x4v){0.f, 0.f, 0.f, 0.f};
            s = __builtin_amdgcn_mfma_f32_16x16x32_bf16(k0, qf0, s, 0, 0, 0);
            s = __builtin_amdgcn_mfma_f32_16x16x32_bf16(k1, qf1, s, 0, 0, 0);
            const float p0 = exp2f(s[0] * SCL);
            const float p1 = exp2f(s[1] * SCL);
            const float p2 = exp2f(s[2] * SCL);
            const float p3 = exp2f(s[3] * SCL);
            lsum += (p0 + p1) + (p2 + p3);
            uint2 pk;
            pk.x = pk2bf(p0, p1);
            pk.y = pk2bf(p2, p3);
            *(uint2*)&Ps[w][nt >> 1][col * 32 + (nt & 1) * 16 + quad * 4] = pk;
        }

        // ---- O^T += V^T P^T (Ps wave-private; lgkmcnt orders in-wave) ----
        const frag8 p0 = *(const frag8*)&Ps[w][0][col * 32 + quad * 8];
        const frag8 p1 = *(const frag8*)&Ps[w][1][col * 32 + quad * 8];
#pragma unroll
        for (int dt = 0; dt < 4; ++dt) {
            const frag8 v0 = *(const frag8*)&Vt0[(dt * 16 + col) * 32 + quad * 8];
            const frag8 v1 = *(const frag8*)&Vt1[(dt * 16 + col) * 32 + quad * 8];
            Oacc[dt] = __builtin_amdgcn_mfma_f32_16x16x32_bf16(v0, p0, Oacc[dt], 0, 0, 0);
            Oacc[dt] = __builtin_amdgcn_mfma_f32_16x16x32_bf16(v1, p1, Oacc[dt], 0, 0, 0);
        }
    }

    // ---- epilogue: write partial O (f32) and partial l ----
    lsum += __shfl_xor(lsum, 16);
    lsum += __shfl_xor(lsum, 32);
    float* op = Opart + (((size_t)ks * 16 + bh) * S_LEN + qrow) * 64;
#pragma unroll
    for (int dt = 0; dt < 4; ++dt) {
        float4 o;
        o.x = Oacc[dt][0]; o.y = Oacc[dt][1];
        o.z = Oacc[dt][2]; o.w = Oacc[dt][3];
        *(float4*)(op + dt * 16 + quad * 4) = o;
    }
    if (quad == 0)
        lpart[((size_t)ks * 16 + bh) * S_LEN + qrow] = lsum;
}

// ---------------------------------------------------------------------------
// Combine K-split partials: ctx[q][hh*64+d] = sum_ks O / sum_ks l  (bf16)
// ---------------------------------------------------------------------------
__global__ __launch_bounds__(256) void attn_combine(const float* __restrict__ Opart,
                                                    const float* __restrict__ lpart,
                                                    u16* __restrict__ ctx)
{
    const int idx = blockIdx.x * 256 + threadIdx.x;  // 0..524287
    const int d4 = idx & 15;
    const int q = (idx >> 4) & (S_LEN - 1);
    const int bh = idx >> 15;
    const int b = bh >> 2, hh = bh & 3;

    float4 o = {0.f, 0.f, 0.f, 0.f};
    float l = 0.f;
#pragma unroll
    for (int ks = 0; ks < KSPLIT; ++ks) {
        const float4 po = *(const float4*)&Opart[
            (((size_t)ks * 16 + bh) * S_LEN + q) * 64 + d4 * 4];
        o.x += po.x; o.y += po.y; o.z += po.z; o.w += po.w;
        l += lpart[((size_t)ks * 16 + bh) * S_LEN + q];
    }
    const float inv = 1.f / l;
    ushort4 r;
    r.x = f2bf(o.x * inv); r.y = f2bf(o.y * inv);
    r.z = f2bf(o.z * inv); r.w = f2bf(o.w * inv);
    *(ushort4*)&ctx[((size_t)(b * S_LEN + q)) * DMODEL + hh * HDIM + d4 * 4] = r;
}

// ---------------------------------------------------------------------------
// h = LayerNorm(h + r); writes fp32 h and bf16 hb
// ---------------------------------------------------------------------------
__global__ __launch_bounds__(256) void add_ln(float* __restrict__ h,
                                              u16* __restrict__ hb,
                                              const float* __restrict__ r,
                                              const float* __restrict__ w,
                                              const float* __restrict__ b)
{
    const int t = blockIdx.x;
    const int d = threadIdx.x;
    const size_t idx = (size_t)t * DMODEL + d;
    const float x = h[idx] + r[idx];

    float s = x, s2 = x * x;
#pragma unroll
    for (int off = 32; off; off >>= 1) {
        s += __shfl_down(s, off);
        s2 += __shfl_down(s2, off);
    }
    __shared__ float ls[4], ls2[4];
    __shared__ float mu_s, rs_s;
    const int wid = d >> 6, lane = d & 63;
    if (lane == 0) { ls[wid] = s; ls2[wid] = s2; }
    __syncthreads();
    if (d == 0) {
        const float ts = ls[0] + ls[1] + ls[2] + ls[3];
        const float ts2 = ls2[0] + ls2[1] + ls2[2] + ls2[3];
        const float mu = ts * (1.f / DMODEL);
        const float var = ts2 * (1.f / DMODEL) - mu * mu;
        mu_s = mu;
        rs_s = rsqrtf(var + EPSV);
    }
    __syncthreads();
    const float y = (x - mu_s) * rs_s * w[d] + b[d];
    h[idx] = y;
    hb[idx] = f2bf(y);
}

__global__ __launch_bounds__(256) void final_proj(const float* __restrict__ h,
                                                  const float* __restrict__ Wfc,
                                                  const float* __restrict__ bfc,
                                                  float* __restrict__ out)
{
    const int idx = blockIdx.x * 256 + threadIdx.x;
    const int b = idx >> 9;
    const int o = idx & 511;
    const float* hp = h + (size_t)(b * S_LEN + S_LEN - 1) * DMODEL;
    const float* wp = Wfc + (size_t)o * DMODEL;
    float s = 0.f;
#pragma unroll 4
    for (int d = 0; d < DMODEL; ++d) s += hp[d] * wp[d];
    out[idx] = s + bfc[o];
}

extern "C" void kernel_launch(void* const* d_in, const int* in_sizes, int n_in,
                              void* d_out, int out_size, void* d_ws, size_t ws_size,
                              hipStream_t stream)
{
    const float* x     = (const float*)d_in[0];
    const float* W_in  = (const float*)d_in[1];
    const float* b_in  = (const float*)d_in[2];
    const float* qkv_w = (const float*)d_in[3];
    const float* qkv_b = (const float*)d_in[4];
    const float* out_w = (const float*)d_in[5];
    const float* out_b = (const float*)d_in[6];
    const float* ln1_w = (const float*)d_in[7];
    const float* ln1_b = (const float*)d_in[8];
    const float* ff1_w = (const float*)d_in[9];
    const float* ff1_b = (const float*)d_in[10];
    const float* ff2_w = (const float*)d_in[11];
    const float* ff2_b = (const float*)d_in[12];
    const float* ln2_w = (const float*)d_in[13];
    const float* ln2_b = (const float*)d_in[14];
    const float* W_fc  = (const float*)d_in[15];
    const float* b_fc  = (const float*)d_in[16];
    float* out = (float*)d_out;

    char* p = (char*)d_ws;
    float* h  = (float*)p; p += (size_t)NTOK * DMODEL * 4;   // 8 MB
    float* sa = (float*)p; p += (size_t)NTOK * DMODEL * 4;   // 8 MB
    u16* hb    = (u16*)p;  p += (size_t)NTOK * DMODEL * 2;   // 4 MB
    u16* xb    = (u16*)p;  p += (size_t)NTOK * INDIM * 2;    // 8 MB
    u16* qkvb  = (u16*)p;  p += (size_t)NTOK * 768 * 2;      // 12 MB
    u16* ctxb  = (u16*)p;  p += (size_t)NTOK * DMODEL * 2;   // 4 MB
    u16* ffb   = (u16*)p;  p += (size_t)NTOK * FFDIM * 2;    // 32 MB
    u16* vtb   = (u16*)p;  p += (size_t)16 * 64 * S_LEN * 2; // 4 MB
    u16* W_in_b  = (u16*)p; p += (size_t)131072 * 2;
    u16* qkv_w_b = (u16*)p; p += (size_t)786432 * 2;
    u16* out_w_b = (u16*)p; p += (size_t)262144 * 2;
    u16* ff1_w_b = (u16*)p; p += (size_t)2097152 * 2;
    u16* ff2_w_b = (u16*)p; p += (size_t)2097152 * 2;
    if (ws_size < (size_t)94633984) return;

    // attention partials alias dead regions (disjoint lifetimes within layer):
    // Opart (32 MB) <- ffb; lpart (512 KB) <- sa
    float* Opart = (float*)ffb;
    float* lpart = sa;

    cvt_all<<<9344, 256, 0, stream>>>(x, W_in, qkv_w, out_w, ff1_w, ff2_w,
                                      xb, W_in_b, qkv_w_b, out_w_b, ff1_w_b, ff2_w_b);

    // input projection + posenc -> h (f32) + hb (bf16)
    gemm64<1><<<dim3(NTOK / 64, DMODEL / 64), 256, 0, stream>>>(
        xb, W_in_b, b_in, h, hb, NTOK, DMODEL, INDIM);

    for (int l = 0; l < NLAYER; ++l) {
        gemm_mfma<0><<<dim3(NTOK / 128, 768 / 128), 256, 0, stream>>>(
            hb, qkv_w_b + (size_t)l * 768 * DMODEL, qkv_b + l * 768,
            qkvb, NTOK, 768, DMODEL);
        vt_prep<<<dim3(16, 32), 256, 0, stream>>>(qkvb, vtb);
        attn_part<<<dim3(BATCH * NHEAD, S_LEN / 64, KSPLIT), 256, 0, stream>>>(
            qkvb, vtb, Opart, lpart);
        attn_combine<<<2048, 256, 0, stream>>>(Opart, lpart, ctxb);
        gemm64<3><<<dim3(NTOK / 64, DMODEL / 64), 256, 0, stream>>>(
            ctxb, out_w_b + (size_t)l * DMODEL * DMODEL, out_b + l * DMODEL,
            sa, nullptr, NTOK, DMODEL, DMODEL);
        add_ln<<<NTOK, 256, 0, stream>>>(h, hb, sa, ln1_w + l * DMODEL, ln1_b + l * DMODEL);
        gemm_mfma<2><<<dim3(NTOK / 128, FFDIM / 128), 256, 0, stream>>>(
            hb, ff1_w_b + (size_t)l * FFDIM * DMODEL, ff1_b + l * FFDIM,
            ffb, NTOK, FFDIM, DMODEL);
        gemm64<3><<<dim3(NTOK / 64, DMODEL / 64), 256, 0, stream>>>(
            ffb, ff2_w_b + (size_t)l * DMODEL * FFDIM, ff2_b + l * DMODEL,
            sa, nullptr, NTOK, DMODEL, FFDIM);
        add_ln<<<NTOK, 256, 0, stream>>>(h, hb, sa, ln2_w + l * DMODEL, ln2_b + l * DMODEL);
    }

    final_proj<<<8, 256, 0, stream>>>(h, W_fc, b_fc, out);
}

// Round 6
// 630.103 us; speedup vs baseline: 11.7697x; 1.0821x over previous
//
#include <hip/hip_runtime.h>
#include <math.h>

#define S_LEN 2048
#define DMODEL 256
#define NHEAD 4
#define HDIM 64
#define NLAYER 4
#define FFDIM 2048
#define INDIM 512
#define BATCH 4
#define NTOK (BATCH * S_LEN) /* 8192 */
#define EPSV 1e-5f
#define KSPLIT 4

typedef __attribute__((ext_vector_type(8))) short frag8;
typedef __attribute__((ext_vector_type(4))) float f32x4v;
typedef unsigned short u16;
typedef unsigned int u32;

// sin/cos positional encoding, matching the JAX reference
__device__ __forceinline__ float pe_val(int s, int d) {
    const float c = 0.035977892f; // ln(10000)/256
    float dv = expf(-(float)(d & ~1) * c);
    float arg = (float)s * dv;
    return (d & 1) ? cosf(arg) : sinf(arg);
}

// fp32 -> bf16 bits, round-to-nearest-even
__device__ __forceinline__ u16 f2bf(float f) {
    union { float f; unsigned u; } v; v.f = f;
    unsigned r = v.u + 0x7fffu + ((v.u >> 16) & 1u);
    return (u16)(r >> 16);
}

// pack two fp32 into (bf16(hi)<<16)|bf16(lo), truncation, single v_perm_b32
__device__ __forceinline__ u32 pk2bf(float lo, float hi) {
    union { float f; u32 u; } a, b; a.f = lo; b.f = hi;
    return __builtin_amdgcn_perm(b.u, a.u, 0x07060302u);
}

// async global->LDS, 16 B per lane; LDS dest = wave-uniform base + lane*16
__device__ __forceinline__ void load_lds16(const u16* g, u16* l) {
    __builtin_amdgcn_global_load_lds(
        (const __attribute__((address_space(1))) unsigned int*)g,
        (__attribute__((address_space(3))) unsigned int*)l, 16, 0, 0);
}

// LDS bank swizzle: tiles are [rows][32 u16]; each 64-B row = 4 chunks of 16 B.
// Physical slot of logical chunk c in row r: c ^ ((r>>1)&3). Since all frag
// reads address rows == col (mod 16), readers use qx = (quad ^ ((col>>1)&3))*8.
// Staging swizzles the global SOURCE address (LDS dest must stay lane-ordered).

// ---------------------------------------------------------------------------
// Convert x + all layer weights fp32 -> bf16 (one launch, float4 granules).
// ---------------------------------------------------------------------------
__global__ __launch_bounds__(256) void cvt_all(
    const float* __restrict__ x, const float* __restrict__ W_in,
    const float* __restrict__ qkv_w, const float* __restrict__ out_w,
    const float* __restrict__ ff1_w, const float* __restrict__ ff2_w,
    u16* __restrict__ xb, u16* __restrict__ W_in_b,
    u16* __restrict__ qkv_w_b, u16* __restrict__ out_w_b,
    u16* __restrict__ ff1_w_b, u16* __restrict__ ff2_w_b)
{
    const int i = blockIdx.x * 256 + threadIdx.x;   // 0..2392063
    const float* src; u16* dst; int base;
    if (i < 1048576)      { src = x;     dst = xb;      base = 0; }
    else if (i < 1081344) { src = W_in;  dst = W_in_b;  base = 1048576; }
    else if (i < 1277952) { src = qkv_w; dst = qkv_w_b; base = 1081344; }
    else if (i < 1343488) { src = out_w; dst = out_w_b; base = 1277952; }
    else if (i < 1867776) { src = ff1_w; dst = ff1_w_b; base = 1343488; }
    else                  { src = ff2_w; dst = ff2_w_b; base = 1867776; }
    const int e = (i - base) * 4;
    const float4 v = *(const float4*)(src + e);
    ushort4 o;
    o.x = f2bf(v.x); o.y = f2bf(v.y); o.z = f2bf(v.z); o.w = f2bf(v.w);
    *(ushort4*)(dst + e) = o;
}

// ---------------------------------------------------------------------------
// bf16 MFMA GEMM, 128x128 tile (m97): C = A @ W^T + bias.  Swizzled LDS.
// MODE 0: bf16 out | MODE 2: relu, bf16 out.
// ---------------------------------------------------------------------------
template <int MODE>
__global__ __launch_bounds__(256) void gemm_mfma(
    const u16* __restrict__ A, const u16* __restrict__ W,
    const float* __restrict__ bias, u16* __restrict__ Cb,
    int M, int N, int K)
{
    __shared__ __align__(16) u16 As[128 * 32];
    __shared__ __align__(16) u16 Bs[128 * 32];
    const int t = threadIdx.x;
    const int w = t >> 6, lane = t & 63;
    const int col = lane & 15, quad = lane >> 4;
    const int qx = (quad ^ ((col >> 1) & 3)) * 8;   // swizzled read slot
    const int m0 = blockIdx.x * 128, n0 = blockIdx.y * 128;
    const int wm = (w >> 1) * 64, wn = (w & 1) * 64;

    const int r0 = lane >> 2;
    const int kc = ((lane & 3) ^ ((lane >> 3) & 3)) * 8;  // swizzled source seg
    const u16* pA0 = A + (size_t)(m0 + (w * 2 + 0) * 16 + r0) * K + kc;
    const u16* pA1 = A + (size_t)(m0 + (w * 2 + 1) * 16 + r0) * K + kc;
    const u16* pB0 = W + (size_t)(n0 + (w * 2 + 0) * 16 + r0) * K + kc;
    const u16* pB1 = W + (size_t)(n0 + (w * 2 + 1) * 16 + r0) * K + kc;
    u16* lA0 = As + (w * 2 + 0) * 512;
    u16* lA1 = As + (w * 2 + 1) * 512;
    u16* lB0 = Bs + (w * 2 + 0) * 512;
    u16* lB1 = Bs + (w * 2 + 1) * 512;

    f32x4v acc[4][4];
#pragma unroll
    for (int i = 0; i < 4; ++i)
#pragma unroll
        for (int j = 0; j < 4; ++j) acc[i][j] = (f32x4v){0.f, 0.f, 0.f, 0.f};

    for (int kb = 0; kb < K; kb += 32) {
        __syncthreads();
        load_lds16(pA0 + kb, lA0);
        load_lds16(pA1 + kb, lA1);
        load_lds16(pB0 + kb, lB0);
        load_lds16(pB1 + kb, lB1);
        __syncthreads();

        frag8 a[4], b[4];
#pragma unroll
        for (int i = 0; i < 4; ++i)
            a[i] = *(const frag8*)&As[(wm + i * 16 + col) * 32 + qx];
#pragma unroll
        for (int j = 0; j < 4; ++j)
            b[j] = *(const frag8*)&Bs[(wn + j * 16 + col) * 32 + qx];
#pragma unroll
        for (int i = 0; i < 4; ++i)
#pragma unroll
            for (int j = 0; j < 4; ++j)
                acc[i][j] = __builtin_amdgcn_mfma_f32_16x16x32_bf16(
                    a[i], b[j], acc[i][j], 0, 0, 0);
    }

#pragma unroll
    for (int j = 0; j < 4; ++j) {
        const int cn = n0 + wn + j * 16 + col;
        const float bv = bias[cn];
#pragma unroll
        for (int i = 0; i < 4; ++i) {
#pragma unroll
            for (int r = 0; r < 4; ++r) {
                const int cm = m0 + wm + i * 16 + quad * 4 + r;
                float v = acc[i][j][r] + bv;
                if (MODE == 2) v = fmaxf(v, 0.f);
                Cb[(size_t)cm * N + cn] = f2bf(v);
            }
        }
    }
}

// ---------------------------------------------------------------------------
// bf16 MFMA GEMM, 64x64 tile for N=256 shapes.  Swizzled LDS.
// MODE 1: +posenc, writes f32 + bf16 | MODE 3: writes f32 only.
// ---------------------------------------------------------------------------
template <int MODE>
__global__ __launch_bounds__(256) void gemm64(
    const u16* __restrict__ A, const u16* __restrict__ W,
    const float* __restrict__ bias,
    float* __restrict__ Cf, u16* __restrict__ Cb,
    int M, int N, int K)
{
    __shared__ __align__(16) u16 As[64 * 32];
    __shared__ __align__(16) u16 Bs[64 * 32];
    const int t = threadIdx.x;
    const int w = t >> 6, lane = t & 63;
    const int col = lane & 15, quad = lane >> 4;
    const int qx = (quad ^ ((col >> 1) & 3)) * 8;
    const int m0 = blockIdx.x * 64, n0 = blockIdx.y * 64;
    const int wm = (w >> 1) * 32, wn = (w & 1) * 32;

    const int r0 = lane >> 2;
    const int kc = ((lane & 3) ^ ((lane >> 3) & 3)) * 8;
    const u16* pA = A + (size_t)(m0 + w * 16 + r0) * K + kc;
    const u16* pB = W + (size_t)(n0 + w * 16 + r0) * K + kc;
    u16* lA = As + w * 512;
    u16* lB = Bs + w * 512;

    f32x4v acc[2][2];
#pragma unroll
    for (int i = 0; i < 2; ++i)
#pragma unroll
        for (int j = 0; j < 2; ++j) acc[i][j] = (f32x4v){0.f, 0.f, 0.f, 0.f};

    for (int kb = 0; kb < K; kb += 32) {
        __syncthreads();
        load_lds16(pA + kb, lA);
        load_lds16(pB + kb, lB);
        __syncthreads();

        frag8 a[2], b[2];
#pragma unroll
        for (int i = 0; i < 2; ++i)
            a[i] = *(const frag8*)&As[(wm + i * 16 + col) * 32 + qx];
#pragma unroll
        for (int j = 0; j < 2; ++j)
            b[j] = *(const frag8*)&Bs[(wn + j * 16 + col) * 32 + qx];
#pragma unroll
        for (int i = 0; i < 2; ++i)
#pragma unroll
            for (int j = 0; j < 2; ++j)
                acc[i][j] = __builtin_amdgcn_mfma_f32_16x16x32_bf16(
                    a[i], b[j], acc[i][j], 0, 0, 0);
    }

#pragma unroll
    for (int j = 0; j < 2; ++j) {
        const int cn = n0 + wn + j * 16 + col;
        const float bv = bias[cn];
#pragma unroll
        for (int i = 0; i < 2; ++i) {
#pragma unroll
            for (int r = 0; r < 4; ++r) {
                const int cm = m0 + wm + i * 16 + quad * 4 + r;
                float v = acc[i][j][r] + bv;
                if (MODE == 1) v += pe_val(cm & (S_LEN - 1), cn);
                Cf[(size_t)cm * N + cn] = v;
                if (MODE == 1) Cb[(size_t)cm * N + cn] = f2bf(v);
            }
        }
    }
}

// ---------------------------------------------------------------------------
// vt_prep: per layer, transpose V out of qkv into vt[bh][d][s] (bf16).
// ---------------------------------------------------------------------------
#define PADW 72
__global__ __launch_bounds__(256) void vt_prep(const u16* __restrict__ qkv,
                                               u16* __restrict__ vt)
{
    __shared__ __align__(16) u16 Vl[64][PADW];
    const int t = threadIdx.x;
    const int bh = blockIdx.x, b = bh >> 2, hh = bh & 3;
    const int st = blockIdx.y;
    {
        const int row = t >> 2, seg = (t & 3) * 16;
        const u16* src = qkv + (size_t)(b * S_LEN + st * 64 + row) * 768
                         + 512 + hh * HDIM + seg;
        *(frag8*)&Vl[row][seg]     = *(const frag8*)src;
        *(frag8*)&Vl[row][seg + 8] = *(const frag8*)(src + 8);
    }
    __syncthreads();
    const int d = t >> 2, s0 = (t & 3) * 16;
    frag8 v0, v1;
#pragma unroll
    for (int i = 0; i < 8; ++i) v0[i] = (short)Vl[s0 + i][d];
#pragma unroll
    for (int i = 0; i < 8; ++i) v1[i] = (short)Vl[s0 + 8 + i][d];
    u16* dst = vt + ((size_t)bh * 64 + d) * S_LEN + st * 64 + s0;
    *(frag8*)dst = v0;
    *(frag8*)(dst + 8) = v1;
}

// ---------------------------------------------------------------------------
// Flash attention, K-split partial pass. No-max softmax (scores ~ +-1 here;
// exp2 overflow needs |s|>800): p = exp2(s*scl); partials combine linearly.
// Each wave handles 32 queries (2 q-groups) sharing every K/V frag read.
// All LDS tiles are swizzled [64][32]-u16 chunk layouts, staged via
// global_load_lds with swizzled source addresses.
// ---------------------------------------------------------------------------
__global__ __launch_bounds__(256) void attn_part(const u16* __restrict__ qkv,
                                                 const u16* __restrict__ vt,
                                                 float* __restrict__ Opart,
                                                 float* __restrict__ lpart)
{
    __shared__ __align__(16) u16 Ks0[64 * 32], Ks1[64 * 32];
    __shared__ __align__(16) u16 Vt0[64 * 32], Vt1[64 * 32];
    __shared__ __align__(16) u16 Ps[4][2][2][512];   // [wave][qg][key-half]

    const int t = threadIdx.x;
    const int w = t >> 6, lane = t & 63;
    const int col = lane & 15, quad = lane >> 4;
    const int sq = (col >> 1) & 3;
    const int qx = (quad ^ sq) * 8;
    const int bh = blockIdx.x, b = bh >> 2, hh = bh & 3;
    const int qt = blockIdx.y, ks = blockIdx.z;

    // Q as B-operand for two query groups
    frag8 qf[2][2];
#pragma unroll
    for (int qg = 0; qg < 2; ++qg) {
        const int qrow = qt * 128 + w * 32 + qg * 16 + col;
        const u16* qp = qkv + (size_t)(b * S_LEN + qrow) * 768 + hh * HDIM;
        qf[qg][0] = *(const frag8*)(qp + quad * 8);
        qf[qg][1] = *(const frag8*)(qp + 32 + quad * 8);
    }

    f32x4v Oacc[2][4];
#pragma unroll
    for (int qg = 0; qg < 2; ++qg)
#pragma unroll
        for (int dt = 0; dt < 4; ++dt) Oacc[qg][dt] = (f32x4v){0.f, 0.f, 0.f, 0.f};
    float lsum[2] = {0.f, 0.f};
    const float SCL = 0.125f * 1.44269504f;  // log2(e)/8

    // staging: lane covers row w*16 + lane/4, swizzled 16-B seg
    const int srow = w * 16 + (lane >> 2);
    const int sseg = ((lane & 3) ^ ((lane >> 3) & 3)) * 8;
    const int kb0 = ks * (S_LEN / KSPLIT);
    const u16* kbase = qkv + (size_t)(b * S_LEN + kb0 + srow) * 768
                       + 256 + hh * HDIM + sseg;
    const u16* vbase = vt + ((size_t)bh * 64 + srow) * S_LEN + kb0 + sseg;
    u16* lK0 = Ks0 + w * 512;
    u16* lK1 = Ks1 + w * 512;
    u16* lV0 = Vt0 + w * 512;
    u16* lV1 = Vt1 + w * 512;

    for (int kt = 0; kt < S_LEN / KSPLIT / 64; ++kt) {   // 8 tiles
        __syncthreads();
        const u16* kp = kbase + (size_t)kt * 64 * 768;
        const u16* vp = vbase + kt * 64;
        load_lds16(kp, lK0);        // K dims 0..31
        load_lds16(kp + 32, lK1);   // K dims 32..63
        load_lds16(vp, lV0);        // V^T keys 0..31
        load_lds16(vp + 32, lV1);   // V^T keys 32..63
        __syncthreads();

        // ---- S^T = K Q^T; both q-groups share each K frag read ----
#pragma unroll
        for (int nt = 0; nt < 4; ++nt) {
            const frag8 k0 = *(const frag8*)&Ks0[(nt * 16 + col) * 32 + qx];
            const frag8 k1 = *(const frag8*)&Ks1[(nt * 16 + col) * 32 + qx];
            const int c = (nt & 1) * 2 + (quad >> 1);       // logical key chunk
            const int poff = col * 32 + ((c ^ sq) * 8) + (quad & 1) * 4;
#pragma unroll
            for (int qg = 0; qg < 2; ++qg) {
                f32x4v s = (f32x4v){0.f, 0.f, 0.f, 0.f};
                s = __builtin_amdgcn_mfma_f32_16x16x32_bf16(k0, qf[qg][0], s, 0, 0, 0);
                s = __builtin_amdgcn_mfma_f32_16x16x32_bf16(k1, qf[qg][1], s, 0, 0, 0);
                const float p0 = exp2f(s[0] * SCL);
                const float p1 = exp2f(s[1] * SCL);
                const float p2 = exp2f(s[2] * SCL);
                const float p3 = exp2f(s[3] * SCL);
                lsum[qg] += (p0 + p1) + (p2 + p3);
                uint2 pk;
                pk.x = pk2bf(p0, p1);
                pk.y = pk2bf(p2, p3);
                *(uint2*)&Ps[w][qg][nt >> 1][poff] = pk;
            }
        }

        // ---- O^T += V^T P^T; both q-groups share each V frag read ----
        frag8 pf[2][2];
#pragma unroll
        for (int qg = 0; qg < 2; ++qg) {
            pf[qg][0] = *(const frag8*)&Ps[w][qg][0][col * 32 + qx];
            pf[qg][1] = *(const frag8*)&Ps[w][qg][1][col * 32 + qx];
        }
#pragma unroll
        for (int dt = 0; dt < 4; ++dt) {
            const frag8 v0 = *(const frag8*)&Vt0[(dt * 16 + col) * 32 + qx];
            const frag8 v1 = *(const frag8*)&Vt1[(dt * 16 + col) * 32 + qx];
#pragma unroll
            for (int qg = 0; qg < 2; ++qg) {
                Oacc[qg][dt] = __builtin_amdgcn_mfma_f32_16x16x32_bf16(
                    v0, pf[qg][0], Oacc[qg][dt], 0, 0, 0);
                Oacc[qg][dt] = __builtin_amdgcn_mfma_f32_16x16x32_bf16(
                    v1, pf[qg][1], Oacc[qg][dt], 0, 0, 0);
            }
        }
    }

    // ---- epilogue: write partial O (f32) and partial l per q-group ----
#pragma unroll
    for (int qg = 0; qg < 2; ++qg) {
        float ls = lsum[qg];
        ls += __shfl_xor(ls, 16);
        ls += __shfl_xor(ls, 32);
        const int qrow = qt * 128 + w * 32 + qg * 16 + col;
        float* op = Opart + (((size_t)ks * 16 + bh) * S_LEN + qrow) * 64;
#pragma unroll
        for (int dt = 0; dt < 4; ++dt) {
            float4 o;
            o.x = Oacc[qg][dt][0]; o.y = Oacc[qg][dt][1];
            o.z = Oacc[qg][dt][2]; o.w = Oacc[qg][dt][3];
            *(float4*)(op + dt * 16 + quad * 4) = o;
        }
        if (quad == 0)
            lpart[((size_t)ks * 16 + bh) * S_LEN + qrow] = ls;
    }
}

// ---------------------------------------------------------------------------
// Combine K-split partials: ctx[q][hh*64+d] = sum_ks O / sum_ks l  (bf16)
// ---------------------------------------------------------------------------
__global__ __launch_bounds__(256) void attn_combine(const float* __restrict__ Opart,
                                                    const float* __restrict__ lpart,
                                                    u16* __restrict__ ctx)
{
    const int idx = blockIdx.x * 256 + threadIdx.x;  // 0..524287
    const int d4 = idx & 15;
    const int q = (idx >> 4) & (S_LEN - 1);
    const int bh = idx >> 15;
    const int b = bh >> 2, hh = bh & 3;

    float4 o = {0.f, 0.f, 0.f, 0.f};
    float l = 0.f;
#pragma unroll
    for (int ks = 0; ks < KSPLIT; ++ks) {
        const float4 po = *(const float4*)&Opart[
            (((size_t)ks * 16 + bh) * S_LEN + q) * 64 + d4 * 4];
        o.x += po.x; o.y += po.y; o.z += po.z; o.w += po.w;
        l += lpart[((size_t)ks * 16 + bh) * S_LEN + q];
    }
    const float inv = 1.f / l;
    ushort4 r;
    r.x = f2bf(o.x * inv); r.y = f2bf(o.y * inv);
    r.z = f2bf(o.z * inv); r.w = f2bf(o.w * inv);
    *(ushort4*)&ctx[((size_t)(b * S_LEN + q)) * DMODEL + hh * HDIM + d4 * 4] = r;
}

// ---------------------------------------------------------------------------
// h = LayerNorm(h + r); writes fp32 h and bf16 hb
// ---------------------------------------------------------------------------
__global__ __launch_bounds__(256) void add_ln(float* __restrict__ h,
                                              u16* __restrict__ hb,
                                              const float* __restrict__ r,
                                              const float* __restrict__ w,
                                              const float* __restrict__ b)
{
    const int t = blockIdx.x;
    const int d = threadIdx.x;
    const size_t idx = (size_t)t * DMODEL + d;
    const float x = h[idx] + r[idx];

    float s = x, s2 = x * x;
#pragma unroll
    for (int off = 32; off; off >>= 1) {
        s += __shfl_down(s, off);
        s2 += __shfl_down(s2, off);
    }
    __shared__ float ls[4], ls2[4];
    __shared__ float mu_s, rs_s;
    const int wid = d >> 6, lane = d & 63;
    if (lane == 0) { ls[wid] = s; ls2[wid] = s2; }
    __syncthreads();
    if (d == 0) {
        const float ts = ls[0] + ls[1] + ls[2] + ls[3];
        const float ts2 = ls2[0] + ls2[1] + ls2[2] + ls2[3];
        const float mu = ts * (1.f / DMODEL);
        const float var = ts2 * (1.f / DMODEL) - mu * mu;
        mu_s = mu;
        rs_s = rsqrtf(var + EPSV);
    }
    __syncthreads();
    const float y = (x - mu_s) * rs_s * w[d] + b[d];
    h[idx] = y;
    hb[idx] = f2bf(y);
}

__global__ __launch_bounds__(256) void final_proj(const float* __restrict__ h,
                                                  const float* __restrict__ Wfc,
                                                  const float* __restrict__ bfc,
                                                  float* __restrict__ out)
{
    const int idx = blockIdx.x * 256 + threadIdx.x;
    const int b = idx >> 9;
    const int o = idx & 511;
    const float* hp = h + (size_t)(b * S_LEN + S_LEN - 1) * DMODEL;
    const float* wp = Wfc + (size_t)o * DMODEL;
    float s = 0.f;
#pragma unroll 4
    for (int d = 0; d < DMODEL; ++d) s += hp[d] * wp[d];
    out[idx] = s + bfc[o];
}

extern "C" void kernel_launch(void* const* d_in, const int* in_sizes, int n_in,
                              void* d_out, int out_size, void* d_ws, size_t ws_size,
                              hipStream_t stream)
{
    const float* x     = (const float*)d_in[0];
    const float* W_in  = (const float*)d_in[1];
    const float* b_in  = (const float*)d_in[2];
    const float* qkv_w = (const float*)d_in[3];
    const float* qkv_b = (const float*)d_in[4];
    const float* out_w = (const float*)d_in[5];
    const float* out_b = (const float*)d_in[6];
    const float* ln1_w = (const float*)d_in[7];
    const float* ln1_b = (const float*)d_in[8];
    const float* ff1_w = (const float*)d_in[9];
    const float* ff1_b = (const float*)d_in[10];
    const float* ff2_w = (const float*)d_in[11];
    const float* ff2_b = (const float*)d_in[12];
    const float* ln2_w = (const float*)d_in[13];
    const float* ln2_b = (const float*)d_in[14];
    const float* W_fc  = (const float*)d_in[15];
    const float* b_fc  = (const float*)d_in[16];
    float* out = (float*)d_out;

    char* p = (char*)d_ws;
    float* h  = (float*)p; p += (size_t)NTOK * DMODEL * 4;   // 8 MB
    float* sa = (float*)p; p += (size_t)NTOK * DMODEL * 4;   // 8 MB
    u16* hb    = (u16*)p;  p += (size_t)NTOK * DMODEL * 2;   // 4 MB
    u16* xb    = (u16*)p;  p += (size_t)NTOK * INDIM * 2;    // 8 MB
    u16* qkvb  = (u16*)p;  p += (size_t)NTOK * 768 * 2;      // 12 MB
    u16* ctxb  = (u16*)p;  p += (size_t)NTOK * DMODEL * 2;   // 4 MB
    u16* ffb   = (u16*)p;  p += (size_t)NTOK * FFDIM * 2;    // 32 MB
    u16* vtb   = (u16*)p;  p += (size_t)16 * 64 * S_LEN * 2; // 4 MB
    u16* W_in_b  = (u16*)p; p += (size_t)131072 * 2;
    u16* qkv_w_b = (u16*)p; p += (size_t)786432 * 2;
    u16* out_w_b = (u16*)p; p += (size_t)262144 * 2;
    u16* ff1_w_b = (u16*)p; p += (size_t)2097152 * 2;
    u16* ff2_w_b = (u16*)p; p += (size_t)2097152 * 2;
    if (ws_size < (size_t)94633984) return;

    // attention partials alias dead regions (disjoint lifetimes within layer):
    // Opart (32 MB) <- ffb; lpart (512 KB) <- sa
    float* Opart = (float*)ffb;
    float* lpart = sa;

    cvt_all<<<9344, 256, 0, stream>>>(x, W_in, qkv_w, out_w, ff1_w, ff2_w,
                                      xb, W_in_b, qkv_w_b, out_w_b, ff1_w_b, ff2_w_b);

    // input projection + posenc -> h (f32) + hb (bf16)
    gemm64<1><<<dim3(NTOK / 64, DMODEL / 64), 256, 0, stream>>>(
        xb, W_in_b, b_in, h, hb, NTOK, DMODEL, INDIM);

    for (int l = 0; l < NLAYER; ++l) {
        gemm_mfma<0><<<dim3(NTOK / 128, 768 / 128), 256, 0, stream>>>(
            hb, qkv_w_b + (size_t)l * 768 * DMODEL, qkv_b + l * 768,
            qkvb, NTOK, 768, DMODEL);
        vt_prep<<<dim3(16, 32), 256, 0, stream>>>(qkvb, vtb);
        attn_part<<<dim3(BATCH * NHEAD, S_LEN / 128, KSPLIT), 256, 0, stream>>>(
            qkvb, vtb, Opart, lpart);
        attn_combine<<<2048, 256, 0, stream>>>(Opart, lpart, ctxb);
        gemm64<3><<<dim3(NTOK / 64, DMODEL / 64), 256, 0, stream>>>(
            ctxb, out_w_b + (size_t)l * DMODEL * DMODEL, out_b + l * DMODEL,
            sa, nullptr, NTOK, DMODEL, DMODEL);
        add_ln<<<NTOK, 256, 0, stream>>>(h, hb, sa, ln1_w + l * DMODEL, ln1_b + l * DMODEL);
        gemm_mfma<2><<<dim3(NTOK / 128, FFDIM / 128), 256, 0, stream>>>(
            hb, ff1_w_b + (size_t)l * FFDIM * DMODEL, ff1_b + l * FFDIM,
            ffb, NTOK, FFDIM, DMODEL);
        gemm64<3><<<dim3(NTOK / 64, DMODEL / 64), 256, 0, stream>>>(
            ffb, ff2_w_b + (size_t)l * DMODEL * FFDIM, ff2_b + l * DMODEL,
            sa, nullptr, NTOK, DMODEL, FFDIM);
        add_ln<<<NTOK, 256, 0, stream>>>(h, hb, sa, ln2_w + l * DMODEL, ln2_b + l * DMODEL);
    }

    final_proj<<<8, 256, 0, stream>>>(h, W_fc, b_fc, out);
}

// Round 7
// 569.878 us; speedup vs baseline: 13.0135x; 1.1057x over previous
//
#include <hip/hip_runtime.h>
#include <math.h>

#define S_LEN 2048
#define DMODEL 256
#define NHEAD 4
#define HDIM 64
#define NLAYER 4
#define FFDIM 2048
#define INDIM 512
#define BATCH 4
#define NTOK (BATCH * S_LEN) /* 8192 */
#define EPSV 1e-5f
#define KSPLIT 4

typedef __attribute__((ext_vector_type(8))) short frag8;
typedef __attribute__((ext_vector_type(4))) float f32x4v;
typedef unsigned short u16;
typedef unsigned int u32;

__device__ __forceinline__ float pe_val(int s, int d) {
    const float c = 0.035977892f; // ln(10000)/256
    float dv = expf(-(float)(d & ~1) * c);
    float arg = (float)s * dv;
    return (d & 1) ? cosf(arg) : sinf(arg);
}

__device__ __forceinline__ u16 f2bf(float f) {
    union { float f; unsigned u; } v; v.f = f;
    unsigned r = v.u + 0x7fffu + ((v.u >> 16) & 1u);
    return (u16)(r >> 16);
}
__device__ __forceinline__ float bf2f(u16 h) {
    union { u32 u; float f; } v; v.u = (u32)h << 16; return v.f;
}
// pack two fp32 into (bf16(hi)<<16)|bf16(lo), truncation, one v_perm_b32
__device__ __forceinline__ u32 pk2bf(float lo, float hi) {
    union { float f; u32 u; } a, b; a.f = lo; b.f = hi;
    return __builtin_amdgcn_perm(b.u, a.u, 0x07060302u);
}
__device__ __forceinline__ void load_lds16(const u16* g, u16* l) {
    __builtin_amdgcn_global_load_lds(
        (const __attribute__((address_space(1))) unsigned int*)g,
        (__attribute__((address_space(3))) unsigned int*)l, 16, 0, 0);
}

// ---------------------------------------------------------------------------
// Convert x + all layer weights fp32 -> bf16 (one launch, float4 granules).
// ---------------------------------------------------------------------------
__global__ __launch_bounds__(256) void cvt_all(
    const float* __restrict__ x, const float* __restrict__ W_in,
    const float* __restrict__ qkv_w, const float* __restrict__ out_w,
    const float* __restrict__ ff1_w, const float* __restrict__ ff2_w,
    u16* __restrict__ xb, u16* __restrict__ W_in_b,
    u16* __restrict__ qkv_w_b, u16* __restrict__ out_w_b,
    u16* __restrict__ ff1_w_b, u16* __restrict__ ff2_w_b)
{
    const int i = blockIdx.x * 256 + threadIdx.x;   // 0..2392063
    const float* src; u16* dst; int base;
    if (i < 1048576)      { src = x;     dst = xb;      base = 0; }
    else if (i < 1081344) { src = W_in;  dst = W_in_b;  base = 1048576; }
    else if (i < 1277952) { src = qkv_w; dst = qkv_w_b; base = 1081344; }
    else if (i < 1343488) { src = out_w; dst = out_w_b; base = 1277952; }
    else if (i < 1867776) { src = ff1_w; dst = ff1_w_b; base = 1343488; }
    else                  { src = ff2_w; dst = ff2_w_b; base = 1867776; }
    const int e = (i - base) * 4;
    const float4 v = *(const float4*)(src + e);
    ushort4 o;
    o.x = f2bf(v.x); o.y = f2bf(v.y); o.z = f2bf(v.z); o.w = f2bf(v.w);
    *(ushort4*)(dst + e) = o;
}

// ---------------------------------------------------------------------------
// bf16 MFMA GEMM, 128x128 tile, BK=32 (m97), swizzled LDS.
// MODE 0: bf16 | MODE 2: relu bf16 | MODE 4: bf16 + V^T side-write (cols>=512
// are V of qkv; epilogue owns 4 consecutive rows per lane -> 8B packed store).
// ---------------------------------------------------------------------------
template <int MODE>
__global__ __launch_bounds__(256) void gemm_mfma(
    const u16* __restrict__ A, const u16* __restrict__ W,
    const float* __restrict__ bias, u16* __restrict__ Cb,
    u16* __restrict__ vt, int M, int N, int K)
{
    __shared__ __align__(16) u16 As[128 * 32];
    __shared__ __align__(16) u16 Bs[128 * 32];
    const int t = threadIdx.x;
    const int w = t >> 6, lane = t & 63;
    const int col = lane & 15, quad = lane >> 4;
    const int qx = (quad ^ ((col >> 1) & 3)) * 8;
    const int m0 = blockIdx.x * 128, n0 = blockIdx.y * 128;
    const int wm = (w >> 1) * 64, wn = (w & 1) * 64;

    const int r0 = lane >> 2;
    const int kc = ((lane & 3) ^ ((lane >> 3) & 3)) * 8;
    const u16* pA0 = A + (size_t)(m0 + (w * 2 + 0) * 16 + r0) * K + kc;
    const u16* pA1 = A + (size_t)(m0 + (w * 2 + 1) * 16 + r0) * K + kc;
    const u16* pB0 = W + (size_t)(n0 + (w * 2 + 0) * 16 + r0) * K + kc;
    const u16* pB1 = W + (size_t)(n0 + (w * 2 + 1) * 16 + r0) * K + kc;
    u16* lA0 = As + (w * 2 + 0) * 512;
    u16* lA1 = As + (w * 2 + 1) * 512;
    u16* lB0 = Bs + (w * 2 + 0) * 512;
    u16* lB1 = Bs + (w * 2 + 1) * 512;

    f32x4v acc[4][4];
#pragma unroll
    for (int i = 0; i < 4; ++i)
#pragma unroll
        for (int j = 0; j < 4; ++j) acc[i][j] = (f32x4v){0.f, 0.f, 0.f, 0.f};

    for (int kb = 0; kb < K; kb += 32) {
        __syncthreads();
        load_lds16(pA0 + kb, lA0);
        load_lds16(pA1 + kb, lA1);
        load_lds16(pB0 + kb, lB0);
        load_lds16(pB1 + kb, lB1);
        __syncthreads();

        frag8 a[4], b[4];
#pragma unroll
        for (int i = 0; i < 4; ++i)
            a[i] = *(const frag8*)&As[(wm + i * 16 + col) * 32 + qx];
#pragma unroll
        for (int j = 0; j < 4; ++j)
            b[j] = *(const frag8*)&Bs[(wn + j * 16 + col) * 32 + qx];
#pragma unroll
        for (int i = 0; i < 4; ++i)
#pragma unroll
            for (int j = 0; j < 4; ++j)
                acc[i][j] = __builtin_amdgcn_mfma_f32_16x16x32_bf16(
                    a[i], b[j], acc[i][j], 0, 0, 0);
    }

#pragma unroll
    for (int j = 0; j < 4; ++j) {
        const int cn = n0 + wn + j * 16 + col;
        const float bv = bias[cn];
#pragma unroll
        for (int i = 0; i < 4; ++i) {
            const int cmb = m0 + wm + i * 16 + quad * 4;
            float vv[4];
#pragma unroll
            for (int r = 0; r < 4; ++r) {
                float v = acc[i][j][r] + bv;
                if (MODE == 2) v = fmaxf(v, 0.f);
                vv[r] = v;
                Cb[(size_t)(cmb + r) * N + cn] = f2bf(v);
            }
            if (MODE == 4 && cn >= 512) {   // V^T side-write: vt[bh][d][s]
                const int dg = cn - 512;
                const int bh = (cmb >> 11) * 4 + (dg >> 6);
                uint2 pk;
                pk.x = ((u32)f2bf(vv[1]) << 16) | f2bf(vv[0]);
                pk.y = ((u32)f2bf(vv[3]) << 16) | f2bf(vv[2]);
                *(uint2*)&vt[((size_t)bh * 64 + (dg & 63)) * S_LEN + (cmb & 2047)] = pk;
            }
        }
    }
}

// ---------------------------------------------------------------------------
// bf16 MFMA GEMM, 64x64 tile, BK=64 (half the barriers of BK=32).
// LDS tiles [64 rows][64 u16] = 8 chunks of 16B/row; phys chunk = c ^ (row&7).
// Readers: row == col (mod 8) -> full 8-way chunk spread, conflict-free.
// MODE 0: bf16 out | MODE 1: +posenc, bf16 out.
// ---------------------------------------------------------------------------
template <int MODE>
__global__ __launch_bounds__(256) void gemm64k(
    const u16* __restrict__ A, const u16* __restrict__ W,
    const float* __restrict__ bias, u16* __restrict__ Cb,
    int M, int N, int K)
{
    __shared__ __align__(16) u16 As[64 * 64];
    __shared__ __align__(16) u16 Bs[64 * 64];
    const int t = threadIdx.x;
    const int w = t >> 6, lane = t & 63;
    const int col = lane & 15, quad = lane >> 4;
    const int px0 = ((quad ^ (col & 7))) * 8;  // k-half 0 chunk offset (elems)
    const int px1 = px0 ^ 32;                  // k-half 1 (chunk ^ 4)
    const int m0 = blockIdx.x * 64, n0 = blockIdx.y * 64;
    const int wm = (w >> 1) * 32, wn = (w & 1) * 32;

    // staging: call c covers rows w*16 + c*8 + (lane>>3); phys chunk lane&7
    const int sr = lane >> 3;                  // 0..7
    const int lc = ((lane & 7) ^ sr) * 8;      // logical source chunk (elems)
    const u16* pA0 = A + (size_t)(m0 + w * 16 + sr) * K + lc;
    const u16* pA1 = A + (size_t)(m0 + w * 16 + 8 + sr) * K + lc;
    const u16* pB0 = W + (size_t)(n0 + w * 16 + sr) * K + lc;
    const u16* pB1 = W + (size_t)(n0 + w * 16 + 8 + sr) * K + lc;
    u16* lA0 = As + (w * 16) * 64;
    u16* lA1 = As + (w * 16 + 8) * 64;
    u16* lB0 = Bs + (w * 16) * 64;
    u16* lB1 = Bs + (w * 16 + 8) * 64;

    f32x4v acc[2][2];
#pragma unroll
    for (int i = 0; i < 2; ++i)
#pragma unroll
        for (int j = 0; j < 2; ++j) acc[i][j] = (f32x4v){0.f, 0.f, 0.f, 0.f};

    for (int kb = 0; kb < K; kb += 64) {
        __syncthreads();
        load_lds16(pA0 + kb, lA0);
        load_lds16(pA1 + kb, lA1);
        load_lds16(pB0 + kb, lB0);
        load_lds16(pB1 + kb, lB1);
        __syncthreads();

#pragma unroll
        for (int kh = 0; kh < 2; ++kh) {
            const int px = kh ? px1 : px0;
            frag8 a[2], b[2];
#pragma unroll
            for (int i = 0; i < 2; ++i)
                a[i] = *(const frag8*)&As[(wm + i * 16 + col) * 64 + px];
#pragma unroll
            for (int j = 0; j < 2; ++j)
                b[j] = *(const frag8*)&Bs[(wn + j * 16 + col) * 64 + px];
#pragma unroll
            for (int i = 0; i < 2; ++i)
#pragma unroll
                for (int j = 0; j < 2; ++j)
                    acc[i][j] = __builtin_amdgcn_mfma_f32_16x16x32_bf16(
                        a[i], b[j], acc[i][j], 0, 0, 0);
        }
    }

#pragma unroll
    for (int j = 0; j < 2; ++j) {
        const int cn = n0 + wn + j * 16 + col;
        const float bv = bias[cn];
#pragma unroll
        for (int i = 0; i < 2; ++i) {
#pragma unroll
            for (int r = 0; r < 4; ++r) {
                const int cm = m0 + wm + i * 16 + quad * 4 + r;
                float v = acc[i][j][r] + bv;
                if (MODE == 1) v += pe_val(cm & (S_LEN - 1), cn);
                Cb[(size_t)cm * N + cn] = f2bf(v);
            }
        }
    }
}

// ---------------------------------------------------------------------------
// Flash attention, K-split partial pass. No-max softmax; scale folded into
// the bf16 Q fragments (p = exp2(s), s pre-scaled by log2(e)/8).
// 32 queries/wave (2 q-groups sharing K/V frag reads); swizzled LDS tiles.
// ---------------------------------------------------------------------------
__global__ __launch_bounds__(256) void attn_part(const u16* __restrict__ qkv,
                                                 const u16* __restrict__ vt,
                                                 float* __restrict__ Opart,
                                                 float* __restrict__ lpart)
{
    __shared__ __align__(16) u16 Ks0[64 * 32], Ks1[64 * 32];
    __shared__ __align__(16) u16 Vt0[64 * 32], Vt1[64 * 32];
    __shared__ __align__(16) u16 Ps[4][2][2][512];   // [wave][qg][key-half]

    const int t = threadIdx.x;
    const int w = t >> 6, lane = t & 63;
    const int col = lane & 15, quad = lane >> 4;
    const int sq = (col >> 1) & 3;
    const int qx = (quad ^ sq) * 8;
    const int bh = blockIdx.x, b = bh >> 2, hh = bh & 3;
    const int qt = blockIdx.y, ks = blockIdx.z;

    const float SCL = 0.125f * 1.44269504f;  // log2(e)/8, folded into Q

    frag8 qf[2][2];
#pragma unroll
    for (int qg = 0; qg < 2; ++qg) {
        const int qrow = qt * 128 + w * 32 + qg * 16 + col;
        const u16* qp = qkv + (size_t)(b * S_LEN + qrow) * 768 + hh * HDIM;
        const frag8 r0 = *(const frag8*)(qp + quad * 8);
        const frag8 r1 = *(const frag8*)(qp + 32 + quad * 8);
#pragma unroll
        for (int e = 0; e < 8; ++e) {
            qf[qg][0][e] = (short)f2bf(bf2f((u16)r0[e]) * SCL);
            qf[qg][1][e] = (short)f2bf(bf2f((u16)r1[e]) * SCL);
        }
    }

    f32x4v Oacc[2][4];
#pragma unroll
    for (int qg = 0; qg < 2; ++qg)
#pragma unroll
        for (int dt = 0; dt < 4; ++dt) Oacc[qg][dt] = (f32x4v){0.f, 0.f, 0.f, 0.f};
    float lsum[2] = {0.f, 0.f};

    const int srow = w * 16 + (lane >> 2);
    const int sseg = ((lane & 3) ^ ((lane >> 3) & 3)) * 8;
    const int kb0 = ks * (S_LEN / KSPLIT);
    const u16* kbase = qkv + (size_t)(b * S_LEN + kb0 + srow) * 768
                       + 256 + hh * HDIM + sseg;
    const u16* vbase = vt + ((size_t)bh * 64 + srow) * S_LEN + kb0 + sseg;
    u16* lK0 = Ks0 + w * 512;
    u16* lK1 = Ks1 + w * 512;
    u16* lV0 = Vt0 + w * 512;
    u16* lV1 = Vt1 + w * 512;

    for (int kt = 0; kt < S_LEN / KSPLIT / 64; ++kt) {   // 8 tiles
        __syncthreads();
        const u16* kp = kbase + (size_t)kt * 64 * 768;
        const u16* vp = vbase + kt * 64;
        load_lds16(kp, lK0);
        load_lds16(kp + 32, lK1);
        load_lds16(vp, lV0);
        load_lds16(vp + 32, lV1);
        __syncthreads();

#pragma unroll
        for (int nt = 0; nt < 4; ++nt) {
            const frag8 k0 = *(const frag8*)&Ks0[(nt * 16 + col) * 32 + qx];
            const frag8 k1 = *(const frag8*)&Ks1[(nt * 16 + col) * 32 + qx];
            const int c = (nt & 1) * 2 + (quad >> 1);
            const int poff = col * 32 + ((c ^ sq) * 8) + (quad & 1) * 4;
#pragma unroll
            for (int qg = 0; qg < 2; ++qg) {
                f32x4v s = (f32x4v){0.f, 0.f, 0.f, 0.f};
                s = __builtin_amdgcn_mfma_f32_16x16x32_bf16(k0, qf[qg][0], s, 0, 0, 0);
                s = __builtin_amdgcn_mfma_f32_16x16x32_bf16(k1, qf[qg][1], s, 0, 0, 0);
                const float p0 = __builtin_amdgcn_exp2f(s[0]);
                const float p1 = __builtin_amdgcn_exp2f(s[1]);
                const float p2 = __builtin_amdgcn_exp2f(s[2]);
                const float p3 = __builtin_amdgcn_exp2f(s[3]);
                lsum[qg] += (p0 + p1) + (p2 + p3);
                uint2 pk;
                pk.x = pk2bf(p0, p1);
                pk.y = pk2bf(p2, p3);
                *(uint2*)&Ps[w][qg][nt >> 1][poff] = pk;
            }
        }

        frag8 pf[2][2];
#pragma unroll
        for (int qg = 0; qg < 2; ++qg) {
            pf[qg][0] = *(const frag8*)&Ps[w][qg][0][col * 32 + qx];
            pf[qg][1] = *(const frag8*)&Ps[w][qg][1][col * 32 + qx];
        }
#pragma unroll
        for (int dt = 0; dt < 4; ++dt) {
            const frag8 v0 = *(const frag8*)&Vt0[(dt * 16 + col) * 32 + qx];
            const frag8 v1 = *(const frag8*)&Vt1[(dt * 16 + col) * 32 + qx];
#pragma unroll
            for (int qg = 0; qg < 2; ++qg) {
                Oacc[qg][dt] = __builtin_amdgcn_mfma_f32_16x16x32_bf16(
                    v0, pf[qg][0], Oacc[qg][dt], 0, 0, 0);
                Oacc[qg][dt] = __builtin_amdgcn_mfma_f32_16x16x32_bf16(
                    v1, pf[qg][1], Oacc[qg][dt], 0, 0, 0);
            }
        }
    }

#pragma unroll
    for (int qg = 0; qg < 2; ++qg) {
        float ls = lsum[qg];
        ls += __shfl_xor(ls, 16);
        ls += __shfl_xor(ls, 32);
        const int qrow = qt * 128 + w * 32 + qg * 16 + col;
        float* op = Opart + (((size_t)ks * 16 + bh) * S_LEN + qrow) * 64;
#pragma unroll
        for (int dt = 0; dt < 4; ++dt) {
            float4 o;
            o.x = Oacc[qg][dt][0]; o.y = Oacc[qg][dt][1];
            o.z = Oacc[qg][dt][2]; o.w = Oacc[qg][dt][3];
            *(float4*)(op + dt * 16 + quad * 4) = o;
        }
        if (quad == 0)
            lpart[((size_t)ks * 16 + bh) * S_LEN + qrow] = ls;
    }
}

// ---------------------------------------------------------------------------
// Combine K-split partials: ctx[q][hh*64+d] = sum_ks O / sum_ks l  (bf16)
// ---------------------------------------------------------------------------
__global__ __launch_bounds__(256) void attn_combine(const float* __restrict__ Opart,
                                                    const float* __restrict__ lpart,
                                                    u16* __restrict__ ctx)
{
    const int idx = blockIdx.x * 256 + threadIdx.x;  // 0..524287
    const int d4 = idx & 15;
    const int q = (idx >> 4) & (S_LEN - 1);
    const int bh = idx >> 15;
    const int b = bh >> 2, hh = bh & 3;

    float4 o = {0.f, 0.f, 0.f, 0.f};
    float l = 0.f;
#pragma unroll
    for (int ks = 0; ks < KSPLIT; ++ks) {
        const float4 po = *(const float4*)&Opart[
            (((size_t)ks * 16 + bh) * S_LEN + q) * 64 + d4 * 4];
        o.x += po.x; o.y += po.y; o.z += po.z; o.w += po.w;
        l += lpart[((size_t)ks * 16 + bh) * S_LEN + q];
    }
    const float inv = 1.f / l;
    ushort4 r;
    r.x = f2bf(o.x * inv); r.y = f2bf(o.y * inv);
    r.z = f2bf(o.z * inv); r.w = f2bf(o.w * inv);
    *(ushort4*)&ctx[((size_t)(b * S_LEN + q)) * DMODEL + hh * HDIM + d4 * 4] = r;
}

// ---------------------------------------------------------------------------
// hb = LayerNorm(hb + r) * w + b, all bf16 in/out (stats in fp32)
// ---------------------------------------------------------------------------
__global__ __launch_bounds__(256) void add_ln(u16* __restrict__ hb,
                                              const u16* __restrict__ r,
                                              const float* __restrict__ w,
                                              const float* __restrict__ b)
{
    const int t = blockIdx.x;
    const int d = threadIdx.x;
    const size_t idx = (size_t)t * DMODEL + d;
    const float x = bf2f(hb[idx]) + bf2f(r[idx]);

    float s = x, s2 = x * x;
#pragma unroll
    for (int off = 32; off; off >>= 1) {
        s += __shfl_down(s, off);
        s2 += __shfl_down(s2, off);
    }
    __shared__ float ls[4], ls2[4];
    __shared__ float mu_s, rs_s;
    const int wid = d >> 6, lane = d & 63;
    if (lane == 0) { ls[wid] = s; ls2[wid] = s2; }
    __syncthreads();
    if (d == 0) {
        const float ts = ls[0] + ls[1] + ls[2] + ls[3];
        const float ts2 = ls2[0] + ls2[1] + ls2[2] + ls2[3];
        const float mu = ts * (1.f / DMODEL);
        const float var = ts2 * (1.f / DMODEL) - mu * mu;
        mu_s = mu;
        rs_s = rsqrtf(var + EPSV);
    }
    __syncthreads();
    hb[idx] = f2bf((x - mu_s) * rs_s * w[d] + b[d]);
}

__global__ __launch_bounds__(256) void final_proj(const u16* __restrict__ hb,
                                                  const float* __restrict__ Wfc,
                                                  const float* __restrict__ bfc,
                                                  float* __restrict__ out)
{
    const int idx = blockIdx.x * 256 + threadIdx.x;
    const int b = idx >> 9;
    const int o = idx & 511;
    const u16* hp = hb + (size_t)(b * S_LEN + S_LEN - 1) * DMODEL;
    const float* wp = Wfc + (size_t)o * DMODEL;
    float s = 0.f;
#pragma unroll 4
    for (int d = 0; d < DMODEL; ++d) s += bf2f(hp[d]) * wp[d];
    out[idx] = s + bfc[o];
}

extern "C" void kernel_launch(void* const* d_in, const int* in_sizes, int n_in,
                              void* d_out, int out_size, void* d_ws, size_t ws_size,
                              hipStream_t stream)
{
    const float* x     = (const float*)d_in[0];
    const float* W_in  = (const float*)d_in[1];
    const float* b_in  = (const float*)d_in[2];
    const float* qkv_w = (const float*)d_in[3];
    const float* qkv_b = (const float*)d_in[4];
    const float* out_w = (const float*)d_in[5];
    const float* out_b = (const float*)d_in[6];
    const float* ln1_w = (const float*)d_in[7];
    const float* ln1_b = (const float*)d_in[8];
    const float* ff1_w = (const float*)d_in[9];
    const float* ff1_b = (const float*)d_in[10];
    const float* ff2_w = (const float*)d_in[11];
    const float* ff2_b = (const float*)d_in[12];
    const float* ln2_w = (const float*)d_in[13];
    const float* ln2_b = (const float*)d_in[14];
    const float* W_fc  = (const float*)d_in[15];
    const float* b_fc  = (const float*)d_in[16];
    float* out = (float*)d_out;

    char* p = (char*)d_ws;
    u16* hb    = (u16*)p;  p += (size_t)NTOK * DMODEL * 2;   // 4 MB
    u16* sab   = (u16*)p;  p += (size_t)NTOK * DMODEL * 2;   // 4 MB
    u16* xb    = (u16*)p;  p += (size_t)NTOK * INDIM * 2;    // 8 MB
    u16* qkvb  = (u16*)p;  p += (size_t)NTOK * 768 * 2;      // 12 MB
    u16* ctxb  = (u16*)p;  p += (size_t)NTOK * DMODEL * 2;   // 4 MB
    u16* ffb   = (u16*)p;  p += (size_t)NTOK * FFDIM * 2;    // 32 MB
    u16* vtb   = (u16*)p;  p += (size_t)16 * 64 * S_LEN * 2; // 4 MB
    u16* W_in_b  = (u16*)p; p += (size_t)131072 * 2;
    u16* qkv_w_b = (u16*)p; p += (size_t)786432 * 2;
    u16* out_w_b = (u16*)p; p += (size_t)262144 * 2;
    u16* ff1_w_b = (u16*)p; p += (size_t)2097152 * 2;
    u16* ff2_w_b = (u16*)p; p += (size_t)2097152 * 2;
    if (ws_size < (size_t)82051072) return;

    // attention partials alias dead regions (disjoint lifetimes within layer):
    // Opart (32 MB) <- ffb; lpart (512 KB) <- sab
    float* Opart = (float*)ffb;
    float* lpart = (float*)sab;

    cvt_all<<<9344, 256, 0, stream>>>(x, W_in, qkv_w, out_w, ff1_w, ff2_w,
                                      xb, W_in_b, qkv_w_b, out_w_b, ff1_w_b, ff2_w_b);

    // input projection + posenc -> hb (bf16)
    gemm64k<1><<<dim3(NTOK / 64, DMODEL / 64), 256, 0, stream>>>(
        xb, W_in_b, b_in, hb, NTOK, DMODEL, INDIM);

    for (int l = 0; l < NLAYER; ++l) {
        gemm_mfma<4><<<dim3(NTOK / 128, 768 / 128), 256, 0, stream>>>(
            hb, qkv_w_b + (size_t)l * 768 * DMODEL, qkv_b + l * 768,
            qkvb, vtb, NTOK, 768, DMODEL);
        attn_part<<<dim3(BATCH * NHEAD, S_LEN / 128, KSPLIT), 256, 0, stream>>>(
            qkvb, vtb, Opart, lpart);
        attn_combine<<<2048, 256, 0, stream>>>(Opart, lpart, ctxb);
        gemm64k<0><<<dim3(NTOK / 64, DMODEL / 64), 256, 0, stream>>>(
            ctxb, out_w_b + (size_t)l * DMODEL * DMODEL, out_b + l * DMODEL,
            sab, NTOK, DMODEL, DMODEL);
        add_ln<<<NTOK, 256, 0, stream>>>(hb, sab, ln1_w + l * DMODEL, ln1_b + l * DMODEL);
        gemm_mfma<2><<<dim3(NTOK / 128, FFDIM / 128), 256, 0, stream>>>(
            hb, ff1_w_b + (size_t)l * FFDIM * DMODEL, ff1_b + l * FFDIM,
            ffb, nullptr, NTOK, FFDIM, DMODEL);
        gemm64k<0><<<dim3(NTOK / 64, DMODEL / 64), 256, 0, stream>>>(
            ffb, ff2_w_b + (size_t)l * DMODEL * FFDIM, ff2_b + l * DMODEL,
            sab, NTOK, DMODEL, FFDIM);
        add_ln<<<NTOK, 256, 0, stream>>>(hb, sab, ln2_w + l * DMODEL, ln2_b + l * DMODEL);
    }

    final_proj<<<8, 256, 0, stream>>>(hb, W_fc, b_fc, out);
}

// Round 8
// 566.654 us; speedup vs baseline: 13.0876x; 1.0057x over previous
//
#include <hip/hip_runtime.h>
#include <math.h>

#define S_LEN 2048
#define DMODEL 256
#define NHEAD 4
#define HDIM 64
#define NLAYER 4
#define FFDIM 2048
#define INDIM 512
#define BATCH 4
#define NTOK (BATCH * S_LEN) /* 8192 */
#define EPSV 1e-5f
#define KSPLIT 4

typedef __attribute__((ext_vector_type(8))) short frag8;
typedef __attribute__((ext_vector_type(4))) float f32x4v;
typedef unsigned short u16;
typedef unsigned int u32;

__device__ __forceinline__ float pe_val(int s, int d) {
    const float c = 0.035977892f; // ln(10000)/256
    float dv = expf(-(float)(d & ~1) * c);
    float arg = (float)s * dv;
    return (d & 1) ? cosf(arg) : sinf(arg);
}

__device__ __forceinline__ u16 f2bf(float f) {
    union { float f; unsigned u; } v; v.f = f;
    unsigned r = v.u + 0x7fffu + ((v.u >> 16) & 1u);
    return (u16)(r >> 16);
}
__device__ __forceinline__ float bf2f(u16 h) {
    union { u32 u; float f; } v; v.u = (u32)h << 16; return v.f;
}
// pack two fp32 into (bf16(hi)<<16)|bf16(lo), truncation, one v_perm_b32
__device__ __forceinline__ u32 pk2bf(float lo, float hi) {
    union { float f; u32 u; } a, b; a.f = lo; b.f = hi;
    return __builtin_amdgcn_perm(b.u, a.u, 0x07060302u);
}
__device__ __forceinline__ void load_lds16(const u16* g, u16* l) {
    __builtin_amdgcn_global_load_lds(
        (const __attribute__((address_space(1))) unsigned int*)g,
        (__attribute__((address_space(3))) unsigned int*)l, 16, 0, 0);
}

// ---------------------------------------------------------------------------
// Convert x + all layer weights fp32 -> bf16 (one launch, float4 granules).
// ---------------------------------------------------------------------------
__global__ __launch_bounds__(256) void cvt_all(
    const float* __restrict__ x, const float* __restrict__ W_in,
    const float* __restrict__ qkv_w, const float* __restrict__ out_w,
    const float* __restrict__ ff1_w, const float* __restrict__ ff2_w,
    u16* __restrict__ xb, u16* __restrict__ W_in_b,
    u16* __restrict__ qkv_w_b, u16* __restrict__ out_w_b,
    u16* __restrict__ ff1_w_b, u16* __restrict__ ff2_w_b)
{
    const int i = blockIdx.x * 256 + threadIdx.x;   // 0..2392063
    const float* src; u16* dst; int base;
    if (i < 1048576)      { src = x;     dst = xb;      base = 0; }
    else if (i < 1081344) { src = W_in;  dst = W_in_b;  base = 1048576; }
    else if (i < 1277952) { src = qkv_w; dst = qkv_w_b; base = 1081344; }
    else if (i < 1343488) { src = out_w; dst = out_w_b; base = 1277952; }
    else if (i < 1867776) { src = ff1_w; dst = ff1_w_b; base = 1343488; }
    else                  { src = ff2_w; dst = ff2_w_b; base = 1867776; }
    const int e = (i - base) * 4;
    const float4 v = *(const float4*)(src + e);
    ushort4 o;
    o.x = f2bf(v.x); o.y = f2bf(v.y); o.z = f2bf(v.z); o.w = f2bf(v.w);
    *(ushort4*)(dst + e) = o;
}

// ---------------------------------------------------------------------------
// bf16 MFMA GEMM, 128x128 tile, BK=32 (m97), swizzled LDS.
// MODE 2: relu bf16 (ff1).
// ---------------------------------------------------------------------------
template <int MODE>
__global__ __launch_bounds__(256) void gemm_mfma(
    const u16* __restrict__ A, const u16* __restrict__ W,
    const float* __restrict__ bias, u16* __restrict__ Cb,
    int M, int N, int K)
{
    __shared__ __align__(16) u16 As[128 * 32];
    __shared__ __align__(16) u16 Bs[128 * 32];
    const int t = threadIdx.x;
    const int w = t >> 6, lane = t & 63;
    const int col = lane & 15, quad = lane >> 4;
    const int qx = (quad ^ ((col >> 1) & 3)) * 8;
    const int m0 = blockIdx.x * 128, n0 = blockIdx.y * 128;
    const int wm = (w >> 1) * 64, wn = (w & 1) * 64;

    const int r0 = lane >> 2;
    const int kc = ((lane & 3) ^ ((lane >> 3) & 3)) * 8;
    const u16* pA0 = A + (size_t)(m0 + (w * 2 + 0) * 16 + r0) * K + kc;
    const u16* pA1 = A + (size_t)(m0 + (w * 2 + 1) * 16 + r0) * K + kc;
    const u16* pB0 = W + (size_t)(n0 + (w * 2 + 0) * 16 + r0) * K + kc;
    const u16* pB1 = W + (size_t)(n0 + (w * 2 + 1) * 16 + r0) * K + kc;
    u16* lA0 = As + (w * 2 + 0) * 512;
    u16* lA1 = As + (w * 2 + 1) * 512;
    u16* lB0 = Bs + (w * 2 + 0) * 512;
    u16* lB1 = Bs + (w * 2 + 1) * 512;

    f32x4v acc[4][4];
#pragma unroll
    for (int i = 0; i < 4; ++i)
#pragma unroll
        for (int j = 0; j < 4; ++j) acc[i][j] = (f32x4v){0.f, 0.f, 0.f, 0.f};

    for (int kb = 0; kb < K; kb += 32) {
        __syncthreads();
        load_lds16(pA0 + kb, lA0);
        load_lds16(pA1 + kb, lA1);
        load_lds16(pB0 + kb, lB0);
        load_lds16(pB1 + kb, lB1);
        __syncthreads();

        frag8 a[4], b[4];
#pragma unroll
        for (int i = 0; i < 4; ++i)
            a[i] = *(const frag8*)&As[(wm + i * 16 + col) * 32 + qx];
#pragma unroll
        for (int j = 0; j < 4; ++j)
            b[j] = *(const frag8*)&Bs[(wn + j * 16 + col) * 32 + qx];
#pragma unroll
        for (int i = 0; i < 4; ++i)
#pragma unroll
            for (int j = 0; j < 4; ++j)
                acc[i][j] = __builtin_amdgcn_mfma_f32_16x16x32_bf16(
                    a[i], b[j], acc[i][j], 0, 0, 0);
    }

#pragma unroll
    for (int j = 0; j < 4; ++j) {
        const int cn = n0 + wn + j * 16 + col;
        const float bv = bias[cn];
#pragma unroll
        for (int i = 0; i < 4; ++i) {
            const int cmb = m0 + wm + i * 16 + quad * 4;
#pragma unroll
            for (int r = 0; r < 4; ++r) {
                float v = acc[i][j][r] + bv;
                if (MODE == 2) v = fmaxf(v, 0.f);
                Cb[(size_t)(cmb + r) * N + cn] = f2bf(v);
            }
        }
    }
}

// ---------------------------------------------------------------------------
// bf16 MFMA GEMM, 64x64 tile, BK=64, swizzled LDS ([64][64], chunk^row&7).
// MODE 0: bf16 | MODE 1: +posenc | MODE 4: bf16 + V^T side-write (cols>=512)
// MODE 5: bf16 with fused residual add (Cb = gemm + bias + aux).
// ---------------------------------------------------------------------------
template <int MODE>
__global__ __launch_bounds__(256) void gemm64k(
    const u16* __restrict__ A, const u16* __restrict__ W,
    const float* __restrict__ bias, u16* __restrict__ Cb,
    u16* __restrict__ aux, int M, int N, int K)
{
    __shared__ __align__(16) u16 As[64 * 64];
    __shared__ __align__(16) u16 Bs[64 * 64];
    const int t = threadIdx.x;
    const int w = t >> 6, lane = t & 63;
    const int col = lane & 15, quad = lane >> 4;
    const int px0 = ((quad ^ (col & 7))) * 8;
    const int px1 = px0 ^ 32;
    const int m0 = blockIdx.x * 64, n0 = blockIdx.y * 64;
    const int wm = (w >> 1) * 32, wn = (w & 1) * 32;

    const int sr = lane >> 3;
    const int lc = ((lane & 7) ^ sr) * 8;
    const u16* pA0 = A + (size_t)(m0 + w * 16 + sr) * K + lc;
    const u16* pA1 = A + (size_t)(m0 + w * 16 + 8 + sr) * K + lc;
    const u16* pB0 = W + (size_t)(n0 + w * 16 + sr) * K + lc;
    const u16* pB1 = W + (size_t)(n0 + w * 16 + 8 + sr) * K + lc;
    u16* lA0 = As + (w * 16) * 64;
    u16* lA1 = As + (w * 16 + 8) * 64;
    u16* lB0 = Bs + (w * 16) * 64;
    u16* lB1 = Bs + (w * 16 + 8) * 64;

    f32x4v acc[2][2];
#pragma unroll
    for (int i = 0; i < 2; ++i)
#pragma unroll
        for (int j = 0; j < 2; ++j) acc[i][j] = (f32x4v){0.f, 0.f, 0.f, 0.f};

    for (int kb = 0; kb < K; kb += 64) {
        __syncthreads();
        load_lds16(pA0 + kb, lA0);
        load_lds16(pA1 + kb, lA1);
        load_lds16(pB0 + kb, lB0);
        load_lds16(pB1 + kb, lB1);
        __syncthreads();

#pragma unroll
        for (int kh = 0; kh < 2; ++kh) {
            const int px = kh ? px1 : px0;
            frag8 a[2], b[2];
#pragma unroll
            for (int i = 0; i < 2; ++i)
                a[i] = *(const frag8*)&As[(wm + i * 16 + col) * 64 + px];
#pragma unroll
            for (int j = 0; j < 2; ++j)
                b[j] = *(const frag8*)&Bs[(wn + j * 16 + col) * 64 + px];
#pragma unroll
            for (int i = 0; i < 2; ++i)
#pragma unroll
                for (int j = 0; j < 2; ++j)
                    acc[i][j] = __builtin_amdgcn_mfma_f32_16x16x32_bf16(
                        a[i], b[j], acc[i][j], 0, 0, 0);
        }
    }

#pragma unroll
    for (int j = 0; j < 2; ++j) {
        const int cn = n0 + wn + j * 16 + col;
        const float bv = bias[cn];
#pragma unroll
        for (int i = 0; i < 2; ++i) {
            const int cmb = m0 + wm + i * 16 + quad * 4;
            float vv[4];
#pragma unroll
            for (int r = 0; r < 4; ++r) {
                float v = acc[i][j][r] + bv;
                if (MODE == 1) v += pe_val((cmb + r) & (S_LEN - 1), cn);
                if (MODE == 5) v += bf2f(aux[(size_t)(cmb + r) * N + cn]);
                vv[r] = v;
                Cb[(size_t)(cmb + r) * N + cn] = f2bf(v);
            }
            if (MODE == 4 && cn >= 512) {   // V^T side-write: vt[bh][d][s]
                const int dg = cn - 512;
                const int bh = (cmb >> 11) * 4 + (dg >> 6);
                uint2 pk;
                pk.x = ((u32)f2bf(vv[1]) << 16) | f2bf(vv[0]);
                pk.y = ((u32)f2bf(vv[3]) << 16) | f2bf(vv[2]);
                *(uint2*)&aux[((size_t)bh * 64 + (dg & 63)) * S_LEN + (cmb & 2047)] = pk;
            }
        }
    }
}

// ---------------------------------------------------------------------------
// Flash attention, K-split partial pass. No-max softmax; scale folded into
// bf16 Q frags (p = exp2(s)). 32 q/wave (2 q-groups sharing K/V frag reads).
// lsum via ones-MFMA (l[q] = sum_k P[k][q], rows of D all equal).
// Partial O stored bf16 (packed); l stored f32.
// ---------------------------------------------------------------------------
__global__ __launch_bounds__(256) void attn_part(const u16* __restrict__ qkv,
                                                 const u16* __restrict__ vt,
                                                 u16* __restrict__ Opart,
                                                 float* __restrict__ lpart)
{
    __shared__ __align__(16) u16 Ks0[64 * 32], Ks1[64 * 32];
    __shared__ __align__(16) u16 Vt0[64 * 32], Vt1[64 * 32];
    __shared__ __align__(16) u16 Ps[4][2][2][512];   // [wave][qg][key-half]

    const int t = threadIdx.x;
    const int w = t >> 6, lane = t & 63;
    const int col = lane & 15, quad = lane >> 4;
    const int sq = (col >> 1) & 3;
    const int qx = (quad ^ sq) * 8;
    const int bh = blockIdx.x, b = bh >> 2, hh = bh & 3;
    const int qt = blockIdx.y, ks = blockIdx.z;

    const float SCL = 0.125f * 1.44269504f;  // log2(e)/8, folded into Q

    frag8 qf[2][2];
#pragma unroll
    for (int qg = 0; qg < 2; ++qg) {
        const int qrow = qt * 128 + w * 32 + qg * 16 + col;
        const u16* qp = qkv + (size_t)(b * S_LEN + qrow) * 768 + hh * HDIM;
        const frag8 r0 = *(const frag8*)(qp + quad * 8);
        const frag8 r1 = *(const frag8*)(qp + 32 + quad * 8);
#pragma unroll
        for (int e = 0; e < 8; ++e) {
            qf[qg][0][e] = (short)f2bf(bf2f((u16)r0[e]) * SCL);
            qf[qg][1][e] = (short)f2bf(bf2f((u16)r1[e]) * SCL);
        }
    }
    frag8 ones;
#pragma unroll
    for (int e = 0; e < 8; ++e) ones[e] = (short)0x3F80;  // bf16 1.0

    f32x4v Oacc[2][4], lacc[2];
#pragma unroll
    for (int qg = 0; qg < 2; ++qg) {
#pragma unroll
        for (int dt = 0; dt < 4; ++dt) Oacc[qg][dt] = (f32x4v){0.f, 0.f, 0.f, 0.f};
        lacc[qg] = (f32x4v){0.f, 0.f, 0.f, 0.f};
    }

    const int srow = w * 16 + (lane >> 2);
    const int sseg = ((lane & 3) ^ ((lane >> 3) & 3)) * 8;
    const int kb0 = ks * (S_LEN / KSPLIT);
    const u16* kbase = qkv + (size_t)(b * S_LEN + kb0 + srow) * 768
                       + 256 + hh * HDIM + sseg;
    const u16* vbase = vt + ((size_t)bh * 64 + srow) * S_LEN + kb0 + sseg;
    u16* lK0 = Ks0 + w * 512;
    u16* lK1 = Ks1 + w * 512;
    u16* lV0 = Vt0 + w * 512;
    u16* lV1 = Vt1 + w * 512;

    for (int kt = 0; kt < S_LEN / KSPLIT / 64; ++kt) {   // 8 tiles
        __syncthreads();
        const u16* kp = kbase + (size_t)kt * 64 * 768;
        const u16* vp = vbase + kt * 64;
        load_lds16(kp, lK0);
        load_lds16(kp + 32, lK1);
        load_lds16(vp, lV0);
        load_lds16(vp + 32, lV1);
        __syncthreads();

#pragma unroll
        for (int nt = 0; nt < 4; ++nt) {
            const frag8 k0 = *(const frag8*)&Ks0[(nt * 16 + col) * 32 + qx];
            const frag8 k1 = *(const frag8*)&Ks1[(nt * 16 + col) * 32 + qx];
            const int c = (nt & 1) * 2 + (quad >> 1);
            const int poff = col * 32 + ((c ^ sq) * 8) + (quad & 1) * 4;
#pragma unroll
            for (int qg = 0; qg < 2; ++qg) {
                f32x4v s = (f32x4v){0.f, 0.f, 0.f, 0.f};
                s = __builtin_amdgcn_mfma_f32_16x16x32_bf16(k0, qf[qg][0], s, 0, 0, 0);
                s = __builtin_amdgcn_mfma_f32_16x16x32_bf16(k1, qf[qg][1], s, 0, 0, 0);
                const float p0 = __builtin_amdgcn_exp2f(s[0]);
                const float p1 = __builtin_amdgcn_exp2f(s[1]);
                const float p2 = __builtin_amdgcn_exp2f(s[2]);
                const float p3 = __builtin_amdgcn_exp2f(s[3]);
                uint2 pk;
                pk.x = pk2bf(p0, p1);
                pk.y = pk2bf(p2, p3);
                *(uint2*)&Ps[w][qg][nt >> 1][poff] = pk;
            }
        }

        frag8 pf[2][2];
#pragma unroll
        for (int qg = 0; qg < 2; ++qg) {
            pf[qg][0] = *(const frag8*)&Ps[w][qg][0][col * 32 + qx];
            pf[qg][1] = *(const frag8*)&Ps[w][qg][1][col * 32 + qx];
        }
#pragma unroll
        for (int dt = 0; dt < 4; ++dt) {
            const frag8 v0 = *(const frag8*)&Vt0[(dt * 16 + col) * 32 + qx];
            const frag8 v1 = *(const frag8*)&Vt1[(dt * 16 + col) * 32 + qx];
#pragma unroll
            for (int qg = 0; qg < 2; ++qg) {
                Oacc[qg][dt] = __builtin_amdgcn_mfma_f32_16x16x32_bf16(
                    v0, pf[qg][0], Oacc[qg][dt], 0, 0, 0);
                Oacc[qg][dt] = __builtin_amdgcn_mfma_f32_16x16x32_bf16(
                    v1, pf[qg][1], Oacc[qg][dt], 0, 0, 0);
            }
        }
#pragma unroll
        for (int qg = 0; qg < 2; ++qg) {
            lacc[qg] = __builtin_amdgcn_mfma_f32_16x16x32_bf16(
                ones, pf[qg][0], lacc[qg], 0, 0, 0);
            lacc[qg] = __builtin_amdgcn_mfma_f32_16x16x32_bf16(
                ones, pf[qg][1], lacc[qg], 0, 0, 0);
        }
    }

#pragma unroll
    for (int qg = 0; qg < 2; ++qg) {
        const int qrow = qt * 128 + w * 32 + qg * 16 + col;
        u16* op = Opart + (((size_t)ks * 16 + bh) * S_LEN + qrow) * 64;
#pragma unroll
        for (int dt = 0; dt < 4; ++dt) {
            uint2 pk;
            pk.x = pk2bf(Oacc[qg][dt][0], Oacc[qg][dt][1]);
            pk.y = pk2bf(Oacc[qg][dt][2], Oacc[qg][dt][3]);
            *(uint2*)(op + dt * 16 + quad * 4) = pk;
        }
        if (quad == 0)
            lpart[((size_t)ks * 16 + bh) * S_LEN + qrow] = lacc[qg][0];
    }
}

// ---------------------------------------------------------------------------
// Combine K-split partials (bf16 O, f32 l): ctx = sum O / sum l
// ---------------------------------------------------------------------------
__global__ __launch_bounds__(256) void attn_combine(const u16* __restrict__ Opart,
                                                    const float* __restrict__ lpart,
                                                    u16* __restrict__ ctx)
{
    const int idx = blockIdx.x * 256 + threadIdx.x;  // 0..524287
    const int d4 = idx & 15;
    const int q = (idx >> 4) & (S_LEN - 1);
    const int bh = idx >> 15;
    const int b = bh >> 2, hh = bh & 3;

    float o0 = 0.f, o1 = 0.f, o2 = 0.f, o3 = 0.f, l = 0.f;
#pragma unroll
    for (int ks = 0; ks < KSPLIT; ++ks) {
        const ushort4 po = *(const ushort4*)&Opart[
            (((size_t)ks * 16 + bh) * S_LEN + q) * 64 + d4 * 4];
        o0 += bf2f(po.x); o1 += bf2f(po.y);
        o2 += bf2f(po.z); o3 += bf2f(po.w);
        l += lpart[((size_t)ks * 16 + bh) * S_LEN + q];
    }
    const float inv = 1.f / l;
    ushort4 r;
    r.x = f2bf(o0 * inv); r.y = f2bf(o1 * inv);
    r.z = f2bf(o2 * inv); r.w = f2bf(o3 * inv);
    *(ushort4*)&ctx[((size_t)(b * S_LEN + q)) * DMODEL + hh * HDIM + d4 * 4] = r;
}

// ---------------------------------------------------------------------------
// hb = LayerNorm(sab) * w + b  (residual already folded in by GEMM epilogue)
// ---------------------------------------------------------------------------
__global__ __launch_bounds__(256) void ln_only(u16* __restrict__ hb,
                                               const u16* __restrict__ sab,
                                               const float* __restrict__ w,
                                               const float* __restrict__ b)
{
    const int t = blockIdx.x;
    const int d = threadIdx.x;
    const size_t idx = (size_t)t * DMODEL + d;
    const float x = bf2f(sab[idx]);

    float s = x, s2 = x * x;
#pragma unroll
    for (int off = 32; off; off >>= 1) {
        s += __shfl_down(s, off);
        s2 += __shfl_down(s2, off);
    }
    __shared__ float ls[4], ls2[4];
    __shared__ float mu_s, rs_s;
    const int wid = d >> 6, lane = d & 63;
    if (lane == 0) { ls[wid] = s; ls2[wid] = s2; }
    __syncthreads();
    if (d == 0) {
        const float ts = ls[0] + ls[1] + ls[2] + ls[3];
        const float ts2 = ls2[0] + ls2[1] + ls2[2] + ls2[3];
        const float mu = ts * (1.f / DMODEL);
        const float var = ts2 * (1.f / DMODEL) - mu * mu;
        mu_s = mu;
        rs_s = rsqrtf(var + EPSV);
    }
    __syncthreads();
    hb[idx] = f2bf((x - mu_s) * rs_s * w[d] + b[d]);
}

__global__ __launch_bounds__(256) void final_proj(const u16* __restrict__ hb,
                                                  const float* __restrict__ Wfc,
                                                  const float* __restrict__ bfc,
                                                  float* __restrict__ out)
{
    const int idx = blockIdx.x * 256 + threadIdx.x;
    const int b = idx >> 9;
    const int o = idx & 511;
    const u16* hp = hb + (size_t)(b * S_LEN + S_LEN - 1) * DMODEL;
    const float* wp = Wfc + (size_t)o * DMODEL;
    float s = 0.f;
#pragma unroll 4
    for (int d = 0; d < DMODEL; ++d) s += bf2f(hp[d]) * wp[d];
    out[idx] = s + bfc[o];
}

extern "C" void kernel_launch(void* const* d_in, const int* in_sizes, int n_in,
                              void* d_out, int out_size, void* d_ws, size_t ws_size,
                              hipStream_t stream)
{
    const float* x     = (const float*)d_in[0];
    const float* W_in  = (const float*)d_in[1];
    const float* b_in  = (const float*)d_in[2];
    const float* qkv_w = (const float*)d_in[3];
    const float* qkv_b = (const float*)d_in[4];
    const float* out_w = (const float*)d_in[5];
    const float* out_b = (const float*)d_in[6];
    const float* ln1_w = (const float*)d_in[7];
    const float* ln1_b = (const float*)d_in[8];
    const float* ff1_w = (const float*)d_in[9];
    const float* ff1_b = (const float*)d_in[10];
    const float* ff2_w = (const float*)d_in[11];
    const float* ff2_b = (const float*)d_in[12];
    const float* ln2_w = (const float*)d_in[13];
    const float* ln2_b = (const float*)d_in[14];
    const float* W_fc  = (const float*)d_in[15];
    const float* b_fc  = (const float*)d_in[16];
    float* out = (float*)d_out;

    char* p = (char*)d_ws;
    u16* hb    = (u16*)p;  p += (size_t)NTOK * DMODEL * 2;   // 4 MB
    u16* sab   = (u16*)p;  p += (size_t)NTOK * DMODEL * 2;   // 4 MB
    u16* xb    = (u16*)p;  p += (size_t)NTOK * INDIM * 2;    // 8 MB
    u16* qkvb  = (u16*)p;  p += (size_t)NTOK * 768 * 2;      // 12 MB
    u16* ctxb  = (u16*)p;  p += (size_t)NTOK * DMODEL * 2;   // 4 MB
    u16* ffb   = (u16*)p;  p += (size_t)NTOK * FFDIM * 2;    // 32 MB
    u16* vtb   = (u16*)p;  p += (size_t)16 * 64 * S_LEN * 2; // 4 MB
    u16* W_in_b  = (u16*)p; p += (size_t)131072 * 2;
    u16* qkv_w_b = (u16*)p; p += (size_t)786432 * 2;
    u16* out_w_b = (u16*)p; p += (size_t)262144 * 2;
    u16* ff1_w_b = (u16*)p; p += (size_t)2097152 * 2;
    u16* ff2_w_b = (u16*)p; p += (size_t)2097152 * 2;
    if (ws_size < (size_t)82051072) return;

    // attention partials alias dead regions (disjoint lifetimes within layer):
    // Opart bf16 (16 MB) <- ffb; lpart f32 (512 KB) <- sab
    u16* Opart = ffb;
    float* lpart = (float*)sab;

    cvt_all<<<9344, 256, 0, stream>>>(x, W_in, qkv_w, out_w, ff1_w, ff2_w,
                                      xb, W_in_b, qkv_w_b, out_w_b, ff1_w_b, ff2_w_b);

    // input projection + posenc -> hb (bf16)
    gemm64k<1><<<dim3(NTOK / 64, DMODEL / 64), 256, 0, stream>>>(
        xb, W_in_b, b_in, hb, nullptr, NTOK, DMODEL, INDIM);

    for (int l = 0; l < NLAYER; ++l) {
        gemm64k<4><<<dim3(NTOK / 64, 768 / 64), 256, 0, stream>>>(
            hb, qkv_w_b + (size_t)l * 768 * DMODEL, qkv_b + l * 768,
            qkvb, vtb, NTOK, 768, DMODEL);
        attn_part<<<dim3(BATCH * NHEAD, S_LEN / 128, KSPLIT), 256, 0, stream>>>(
            qkvb, vtb, Opart, lpart);
        attn_combine<<<2048, 256, 0, stream>>>(Opart, lpart, ctxb);
        gemm64k<5><<<dim3(NTOK / 64, DMODEL / 64), 256, 0, stream>>>(
            ctxb, out_w_b + (size_t)l * DMODEL * DMODEL, out_b + l * DMODEL,
            sab, hb, NTOK, DMODEL, DMODEL);
        ln_only<<<NTOK, 256, 0, stream>>>(hb, sab, ln1_w + l * DMODEL, ln1_b + l * DMODEL);
        gemm_mfma<2><<<dim3(NTOK / 128, FFDIM / 128), 256, 0, stream>>>(
            hb, ff1_w_b + (size_t)l * FFDIM * DMODEL, ff1_b + l * FFDIM,
            ffb, NTOK, FFDIM, DMODEL);
        gemm64k<5><<<dim3(NTOK / 64, DMODEL / 64), 256, 0, stream>>>(
            ffb, ff2_w_b + (size_t)l * DMODEL * FFDIM, ff2_b + l * DMODEL,
            sab, hb, NTOK, DMODEL, FFDIM);
        ln_only<<<NTOK, 256, 0, stream>>>(hb, sab, ln2_w + l * DMODEL, ln2_b + l * DMODEL);
    }

    final_proj<<<8, 256, 0, stream>>>(hb, W_fc, b_fc, out);
}